// Round 10
// baseline (982.355 us; speedup 1.0000x reference)
//
#include <hip/hip_runtime.h>
#include <hip/hip_bf16.h>

// krignn2: out = C_qk @ inv(C_kk) @ (VALUE*mlp_v(VALUE))
// C_kk = exp(-dist(Ks,Ks)) + 1e-3 I,  Ks = KEY*mlp(KEY), Qs = QUERY*mlp(QUERY).
// Blocked fp32 Cholesky + inverted diag blocks + fused fwd/parallel bwd solve.
// R23: R22's potf z-shadow REMOVED (it slowed potf body 72.7->93us; suspected
//      scratch spill of zinit/zpart + scalar-LDS shadow loop extending every
//      prologue phase). potf_body = R19 verbatim (proven 72.7us). The panel-s
//      contribution to z_{s+1} moves to a block-0-only tail in trsmg(s) (R19's
//      proven tail code, gated blockIdx.x==0; consumed only by the NEXT launch
//      -> launch-boundary ordering, no race). zupd riders (panel s-1 -> z_m,
//      m>=s+1) + merged k_mlp + bstep-512 kept from R22 (950us, passing).
//      Coverage: panel p -> z_{p+1} via trsmg(p) tail; -> z_m (m>=p+2) via
//      zupd @ potf_syrk(p+1). Same kk order + single RMW -> bit-identical.

__device__ __forceinline__ int row_of(int e) {
    int i = (int)((sqrtf(8.0f * (float)e + 1.0f) - 1.0f) * 0.5f);
    while ((i + 1) * (i + 2) / 2 <= e) i++;
    while (i * (i + 1) / 2 > e) i--;
    return i;
}

// ---------------- transpose W2 / Wv2 (for coalesced layer-2 reads) -------------
__global__ void k_transpose(const float* __restrict__ W2, const float* __restrict__ Wv2,
                            float* __restrict__ W2T, float* __restrict__ Wv2T) {
    int tid = blockIdx.x * 256 + threadIdx.x;   // 0..32767
    int e = tid & 16383;
    int r = e >> 7, c = e & 127;
    if (tid < 16384) W2T[c * 128 + r] = W2[e];
    else             Wv2T[c * 128 + r] = Wv2[e];
}

// ---------------- MLP body (Linear->ReLU->Linear->ReLU->Linear) + scale --------
template<int DI, int P>
__device__ __forceinline__ void mlp_body(const float* __restrict__ in,
                                         float* __restrict__ out, int base,
                                         const float* __restrict__ W1,
                                         const float* __restrict__ b1,
                                         const float* __restrict__ W2T,
                                         const float* __restrict__ b2,
                                         const float* __restrict__ W3,
                                         const float* __restrict__ b3) {
    __shared__ float xs[P][DI];
    __shared__ float h1[P][128];
    __shared__ float h2[P][129];
    int t = threadIdx.x;
    for (int i = t; i < P * DI; i += 128) xs[i / DI][i % DI] = in[base * DI + i];
    __syncthreads();
    float w1r[DI];
#pragma unroll
    for (int d = 0; d < DI; d++) w1r[d] = W1[t * DI + d];
    float b1t = b1[t], b2t = b2[t];
#pragma unroll
    for (int p = 0; p < P; p++) {
        float s = b1t;
#pragma unroll
        for (int d = 0; d < DI; d++) s += w1r[d] * xs[p][d];
        h1[p][t] = fmaxf(s, 0.0f);
    }
    __syncthreads();
    float acc[P];
#pragma unroll
    for (int p = 0; p < P; p++) acc[p] = b2t;
    for (int k = 0; k < 128; k++) {
        float w = W2T[k * 128 + t];
#pragma unroll
        for (int p = 0; p < P; p++) acc[p] += w * h1[p][k];
    }
#pragma unroll
    for (int p = 0; p < P; p++) h2[p][t] = fmaxf(acc[p], 0.0f);
    __syncthreads();
    if (t < P * DI) {
        int p = t / DI, d = t % DI;
        float s = b3[d];
        for (int k = 0; k < 128; k++) s += W3[d * 128 + k] * h2[p][k];
        int gi = base * DI + t;
        out[gi] = in[gi] * s;
    }
}

// merged: blocks 0-511 KEY, 512-1023 QUERY, 1024-2047 VALUE
__global__ void k_mlp(const float* __restrict__ KEY, float* __restrict__ Ks,
                      const float* __restrict__ QUERY, float* __restrict__ Qs,
                      const float* __restrict__ VALUE, float* __restrict__ Vs,
                      const float* __restrict__ W1, const float* __restrict__ b1,
                      const float* __restrict__ W2T, const float* __restrict__ b2,
                      const float* __restrict__ W3, const float* __restrict__ b3,
                      const float* __restrict__ Wv1, const float* __restrict__ bv1,
                      const float* __restrict__ Wv2T, const float* __restrict__ bv2,
                      const float* __restrict__ Wv3, const float* __restrict__ bv3) {
    int bx = blockIdx.x;
    if (bx < 512)
        mlp_body<3, 32>(KEY, Ks, bx * 32, W1, b1, W2T, b2, W3, b3);
    else if (bx < 1024)
        mlp_body<3, 32>(QUERY, Qs, (bx - 512) * 32, W1, b1, W2T, b2, W3, b3);
    else
        mlp_body<8, 16>(VALUE, Vs, (bx - 1024) * 16, Wv1, bv1, Wv2T, bv2, Wv3, bv3);
}

// ---------------- build C_kk = exp(-dist) + nugget*I ---------------------------
__global__ void k_buildC(const float* __restrict__ Ks, float* __restrict__ C) {
    long idx = (long)blockIdx.x * 256 + threadIdx.x;  // 16M elements
    int b = (int)(idx >> 20);
    int rem = (int)(idx & 1048575);
    int i = rem >> 10, j = rem & 1023;
    const float* a = Ks + ((long)b * 1024 + i) * 3;
    const float* bb = Ks + ((long)b * 1024 + j) * 3;
    float d0 = a[0] - bb[0], d1 = a[1] - bb[1], d2 = a[2] - bb[2];
    float dist = sqrtf(d0 * d0 + d1 * d1 + d2 * d2 + 1e-12f);
    float v = __expf(-dist);
    if (i == j) v += 1e-3f;
    C[idx] = v;
}

// ---------------- potf body, 512 threads, 4x8 half-tiles (R19 verbatim) --------
// smem layout (floats):
//   T   [0,16896)  128x132
//   cv  [16896,17920)  128x8
//   cw  [17920,18944)  128x8
//   Pn  [18944,19968)  128x8
//   St  [19968,28416)  2 x 32x132 (prologue staging; later Lc[6][32][33])
//   rsd [28416,28544)
//   Wb  [28544,30848)  2 x 32x36 (padded stride 36 -> float4-aligned)
//   zs  [30848,32000)  128x9
__device__ void potf_body(float* __restrict__ C, float* __restrict__ V,
                          float* smem, int o, int last, int b) {
    int tid = threadIdx.x;
    float* A = C + (long)b * 1048576;
    float* Vp = V + (long)b * 8192;
    float (*T)[132]      = (float(*)[132])smem;
    float (*cv)[8]       = (float(*)[8])(smem + 16896);
    float (*cw)[8]       = (float(*)[8])(smem + 17920);
    float (*Pn)[8]       = (float(*)[8])(smem + 18944);
    float (*St)[32][132] = (float(*)[32][132])(smem + 19968);
    float (*Lc)[32][33]  = (float(*)[32][33])(smem + 19968);   // aliases St (disjoint in time)
    float* rsd           = smem + 28416;
    float (*Wb)[32][36]  = (float(*)[32][36])(smem + 28544);
    float (*zs)[9]       = (float(*)[9])(smem + 30848);

    bool active = (tid < 272);
    int ti = 0, tj = 0, hh = 0;
    if (active) { int e = tid >> 1; hh = tid & 1; ti = row_of(e); tj = e - ti * (ti + 1) / 2; }
    int r0 = ti * 8 + hh * 4, c0t = tj * 8;
    int lane = tid & 63;
    int sr = tid >> 2, slk = (tid & 3) * 8;     // prologue staging coords

    // issue prologue stage chunk 0 early (overlaps Treg load)
    if (o > 0) {
        const float* sp = A + (long)(o + sr) * 1024 + (o - 128) + slk;
        float4 v0 = *(const float4*)sp;
        float4 v1 = *(const float4*)(sp + 4);
        St[0][slk    ][sr] = v0.x; St[0][slk + 1][sr] = v0.y;
        St[0][slk + 2][sr] = v0.z; St[0][slk + 3][sr] = v0.w;
        St[0][slk + 4][sr] = v1.x; St[0][slk + 5][sr] = v1.y;
        St[0][slk + 6][sr] = v1.z; St[0][slk + 7][sr] = v1.w;
    }
    // load diag block into registers (4 rows x 8 cols per thread)
    float Treg[4][8];
    if (active) {
        const float* src = A + (long)(o + r0) * 1024 + o + c0t;
#pragma unroll
        for (int i = 0; i < 4; i++) {
            float4 va = *(const float4*)(src + (long)i * 1024);
            float4 vb = *(const float4*)(src + (long)i * 1024 + 4);
            Treg[i][0] = va.x; Treg[i][1] = va.y; Treg[i][2] = va.z; Treg[i][3] = va.w;
            Treg[i][4] = vb.x; Treg[i][5] = vb.y; Treg[i][6] = vb.z; Treg[i][7] = vb.w;
        }
    }
    // ---- prologue: Treg -= Lp @ Lp^T, double-buffered staging ----
    if (o > 0) {
        for (int kc = 0; kc < 4; kc++) {
            __syncthreads();                      // St[kc&1] ready
            if (kc < 3) {                         // issue next chunk now
                const float* sp = A + (long)(o + sr) * 1024 + (o - 128) + (kc + 1) * 32 + slk;
                float4 v0 = *(const float4*)sp;
                float4 v1 = *(const float4*)(sp + 4);
                int nb = (kc + 1) & 1;
                St[nb][slk    ][sr] = v0.x; St[nb][slk + 1][sr] = v0.y;
                St[nb][slk + 2][sr] = v0.z; St[nb][slk + 3][sr] = v0.w;
                St[nb][slk + 4][sr] = v1.x; St[nb][slk + 5][sr] = v1.y;
                St[nb][slk + 6][sr] = v1.z; St[nb][slk + 7][sr] = v1.w;
            }
            if (active) {
                int buf = kc & 1;
#pragma unroll 4
                for (int k = 0; k < 32; k++) {
                    float4 a0 = *(const float4*)&St[buf][k][r0];
                    float4 b0 = *(const float4*)&St[buf][k][c0t];
                    float4 b1 = *(const float4*)&St[buf][k][c0t + 4];
                    float aa[4] = {a0.x, a0.y, a0.z, a0.w};
                    float bb[8] = {b0.x, b0.y, b0.z, b0.w, b1.x, b1.y, b1.z, b1.w};
#pragma unroll
                    for (int i = 0; i < 4; i++)
#pragma unroll
                        for (int j = 0; j < 8; j++) Treg[i][j] -= aa[i] * bb[j];
                }
            }
        }
    }
    // ---- initial dump of column 0 into Pn ----
    if (active && tj == 0) {
#pragma unroll
        for (int i = 0; i < 4; i++) {
            *(float4*)&Pn[r0 + i][0] = make_float4(Treg[i][0], Treg[i][1], Treg[i][2], Treg[i][3]);
            *(float4*)&Pn[r0 + i][4] = make_float4(Treg[i][4], Treg[i][5], Treg[i][6], Treg[i][7]);
        }
    }
    __syncthreads();
    // ---- 16 rank-8 panels, 2 barriers each (R16 proven structure) ----
    for (int jbt = 0; jbt < 16; jbt++) {
        int jb = jbt * 8;
        if (tid < 64) {                           // wave-0 LDL on Pn -> cv, cw
            int r1 = lane, r2 = 64 + lane;
            float v1[8], v2[8], w1[8], w2[8];
#pragma unroll
            for (int q = 0; q < 8; q++) {
                int j = jb + q;
                int jl = j & 63;
                bool hi = (j >= 64);
                float a1 = Pn[r1][q], a2 = Pn[r2][q];
#pragma unroll
                for (int p = 0; p < 8; p++) {
                    if (p < q) {
                        float wj = __shfl(hi ? w2[p] : w1[p], jl);
                        a1 -= v1[p] * wj;
                        a2 -= v2[p] * wj;
                    }
                }
                v1[q] = a1; v2[q] = a2;
                float dj = __shfl(hi ? a2 : a1, jl);
                float dinv = 1.0f / dj;
                w1[q] = a1 * dinv; w2[q] = a2 * dinv;
            }
            *(float4*)&cv[r1][0] = make_float4(v1[0], v1[1], v1[2], v1[3]);
            *(float4*)&cv[r1][4] = make_float4(v1[4], v1[5], v1[6], v1[7]);
            *(float4*)&cv[r2][0] = make_float4(v2[0], v2[1], v2[2], v2[3]);
            *(float4*)&cv[r2][4] = make_float4(v2[4], v2[5], v2[6], v2[7]);
            *(float4*)&cw[r1][0] = make_float4(w1[0], w1[1], w1[2], w1[3]);
            *(float4*)&cw[r1][4] = make_float4(w1[4], w1[5], w1[6], w1[7]);
            *(float4*)&cw[r2][0] = make_float4(w2[0], w2[1], w2[2], w2[3]);
            *(float4*)&cw[r2][4] = make_float4(w2[4], w2[5], w2[6], w2[7]);
        }
        __syncthreads();
        if (active && tj == jbt) {                // panel owners: reload LDL column
#pragma unroll
            for (int i = 0; i < 4; i++) {
                float4 va = *(const float4*)&cv[r0 + i][0];
                float4 vb = *(const float4*)&cv[r0 + i][4];
                Treg[i][0] = va.x; Treg[i][1] = va.y; Treg[i][2] = va.z; Treg[i][3] = va.w;
                Treg[i][4] = vb.x; Treg[i][5] = vb.y; Treg[i][6] = vb.z; Treg[i][7] = vb.w;
            }
        } else if (active && tj > jbt) {          // trailing update (+ fused next dump)
#pragma unroll
            for (int h = 0; h < 2; h++) {
                float va4[4][4], wb4[8][4];
#pragma unroll
                for (int i = 0; i < 4; i++) {
                    float4 v = *(const float4*)&cv[r0 + i][h * 4];
                    va4[i][0] = v.x; va4[i][1] = v.y; va4[i][2] = v.z; va4[i][3] = v.w;
                }
#pragma unroll
                for (int j = 0; j < 8; j++) {
                    float4 v = *(const float4*)&cw[c0t + j][h * 4];
                    wb4[j][0] = v.x; wb4[j][1] = v.y; wb4[j][2] = v.z; wb4[j][3] = v.w;
                }
#pragma unroll
                for (int i = 0; i < 4; i++)
#pragma unroll
                    for (int j = 0; j < 8; j++)
                        Treg[i][j] -= va4[i][0] * wb4[j][0] + va4[i][1] * wb4[j][1]
                                    + va4[i][2] * wb4[j][2] + va4[i][3] * wb4[j][3];
            }
            if (tj == jbt + 1) {                  // next panel column -> Pn
#pragma unroll
                for (int i = 0; i < 4; i++) {
                    *(float4*)&Pn[r0 + i][0] = make_float4(Treg[i][0], Treg[i][1], Treg[i][2], Treg[i][3]);
                    *(float4*)&Pn[r0 + i][4] = make_float4(Treg[i][4], Treg[i][5], Treg[i][6], Treg[i][7]);
                }
            }
        }
        __syncthreads();
    }
    // ---- dump registers (raw LDL lower) to LDS T ----
    if (active) {
#pragma unroll
        for (int i = 0; i < 4; i++) {
            *(float4*)&T[r0 + i][c0t]     = make_float4(Treg[i][0], Treg[i][1], Treg[i][2], Treg[i][3]);
            *(float4*)&T[r0 + i][c0t + 4] = make_float4(Treg[i][4], Treg[i][5], Treg[i][6], Treg[i][7]);
        }
    }
    __syncthreads();
    // ---- LDL -> Cholesky L; ZERO upper half ----
    if (tid < 128) rsd[tid] = rsqrtf(T[tid][tid]);
    __syncthreads();
    {
        int rg = tid >> 5, cg = tid & 31;
#pragma unroll
        for (int j = 0; j < 4; j++) {
            int c = cg + 32 * j;
#pragma unroll
            for (int i = 0; i < 8; i++) {
                int r = rg * 8 + i;
                if (c <= r) T[r][c] *= rsd[c];
                else        T[r][c] = 0.0f;
            }
        }
    }
    __syncthreads();
    // ---- trtri phase 2 (waves 0..3, diag 32x32 inverses) ||
    //      snapshot of original off-diag L blocks into Lc (tid>=256) ----
    {
        int wv = tid >> 6;
        if (wv < 4 && lane < 32) {
            int d0 = wv * 32;
            int j = lane;
            float x[32];
#pragma unroll
            for (int i = 0; i < 32; i++) {
                float dinv = 1.0f / T[d0 + i][d0 + i];
                float s = 0.0f;
#pragma unroll
                for (int k = 0; k < i; k++) s += T[d0 + i][d0 + k] * x[k];
                x[i] = (i == j) ? dinv : -s * dinv;
            }
#pragma unroll
            for (int i = 0; i < 32; i++) T[d0 + i][d0 + j] = x[i];
        }
        if (tid >= 256) {
            // p = i*(i-1)/2 + kb : 0:(1,0) 1:(2,0) 2:(2,1) 3:(3,0) 4:(3,1) 5:(3,2)
            for (int idx = tid - 256; idx < 6144; idx += 256) {
                int p = idx >> 10;
                int e = idx & 1023;
                int r = e >> 5, c = e & 31;
                int i3 = (p == 0) ? 1 : (p <= 2 ? 2 : 3);
                int kb = (p == 0) ? 0 : (p <= 2 ? p - 1 : p - 3);
                Lc[p][r][c] = T[i3 * 32 + r][kb * 32 + c];
            }
        }
    }
    __syncthreads();
    // ---- trtri phase 3: two parallel teams, 3 steps, 2 barriers each. ----
    {
        int team = tid >> 8, ttid = tid & 255;
        int orr = ttid >> 3, oc = (ttid & 7) * 4;
        for (int st = 0; st < 3; st++) {
            int i3, j3;
            if (team == 0) { i3 = st + 1; j3 = 0; }
            else           { i3 = (st == 0) ? 2 : 3; j3 = (st == 2) ? 2 : 1; }
            float w0 = 0, w1 = 0, w2 = 0, w3 = 0;
            for (int kb = j3; kb < i3; kb++) {
                int p = i3 * (i3 - 1) / 2 + kb;
#pragma unroll 8
                for (int kk = 0; kk < 32; kk++) {
                    float l = Lc[p][orr][kk];
                    float4 t = *(const float4*)&T[kb * 32 + kk][j3 * 32 + oc];
                    w0 += l * t.x; w1 += l * t.y; w2 += l * t.z; w3 += l * t.w;
                }
            }
            *(float4*)&Wb[team][orr][oc] = make_float4(w0, w1, w2, w3);
            __syncthreads();
            float v0 = 0, v1 = 0, v2 = 0, v3 = 0;
#pragma unroll 8
            for (int kk = 0; kk < 32; kk++) {
                float l = T[i3 * 32 + orr][i3 * 32 + kk];
                float4 wv = *(const float4*)&Wb[team][kk][oc];
                v0 += l * wv.x; v1 += l * wv.y; v2 += l * wv.z; v3 += l * wv.w;
            }
            T[i3 * 32 + orr][j3 * 32 + oc    ] = -v0;
            T[i3 * 32 + orr][j3 * 32 + oc + 1] = -v1;
            T[i3 * 32 + orr][j3 * 32 + oc + 2] = -v2;
            T[i3 * 32 + orr][j3 * 32 + oc + 3] = -v3;
            __syncthreads();
        }
    }
    // ---- writeback Linv (exact zeros above diagonal) ----
    {
        int r = tid >> 2, c0 = (tid & 3) * 32;
        float* dst = A + (long)(o + r) * 1024 + o + c0;
#pragma unroll
        for (int k = 0; k < 8; k++) {
            int c = c0 + 4 * k;
            *(float4*)(dst + 4 * k) = make_float4(T[r][c], T[r][c + 1], T[r][c + 2], T[r][c + 3]);
        }
    }
    // ---- forward diag step: y = Linv @ z; last block also x = Linv^T y ----
    {
        int k = tid >> 2, c2 = (tid & 3) * 2;
        float2 v = *(const float2*)&Vp[(o + k) * 8 + c2];
        zs[k][c2] = v.x; zs[k][c2 + 1] = v.y;
    }
    __syncthreads();
    {
        int r = tid & 127, c2 = (tid >> 7) * 2;
        float y0 = 0, y1 = 0;
#pragma unroll 8
        for (int k = 0; k < 128; k++) {
            float l = T[r][k];
            y0 += l * zs[k][c2];
            y1 += l * zs[k][c2 + 1];
        }
        if (!last) {
            *(float2*)&Vp[(o + r) * 8 + c2] = make_float2(y0, y1);
        } else {
            __syncthreads();
            zs[r][c2] = y0; zs[r][c2 + 1] = y1;
            __syncthreads();
            float x0 = 0, x1 = 0;
#pragma unroll 8
            for (int k = 0; k < 128; k++) {
                float l = T[k][r];
                x0 += l * zs[k][c2];
                x1 += l * zs[k][c2 + 1];
            }
            *(float2*)&Vp[(o + r) * 8 + c2] = make_float2(x0, x1);
        }
    }
}

// ---------------- syrk body, 512 threads, 4x8 tiles ----------------------------
__device__ void syrk_body(float* __restrict__ C, float* smem,
                          int o, int pti, int ptj, int b) {
    float* A = C + (long)b * 1048576;
    int bi = o + 128 + pti * 128, bj = o + 128 + ptj * 128;
    float (*As)[132] = (float(*)[132])smem;
    float (*Bs)[132] = (float(*)[132])(smem + 4224);
    int tid = threadIdx.x;
    int tx = tid & 15, ty = tid >> 4;       // ty 0..31 (4-row groups)
    float acc[4][8] = {};
    int lr = tid >> 2;
    int lk = (tid & 3) * 8;
    bool diag = (bi == bj);
    for (int kc = 0; kc < 128; kc += 32) {
        {
            const float* src = A + (long)(bi + lr) * 1024 + o + kc + lk;
            float4 v0 = *(const float4*)src;
            float4 v1 = *(const float4*)(src + 4);
            As[lk    ][lr] = v0.x; As[lk + 1][lr] = v0.y;
            As[lk + 2][lr] = v0.z; As[lk + 3][lr] = v0.w;
            As[lk + 4][lr] = v1.x; As[lk + 5][lr] = v1.y;
            As[lk + 6][lr] = v1.z; As[lk + 7][lr] = v1.w;
            if (!diag) {
                const float* sb = A + (long)(bj + lr) * 1024 + o + kc + lk;
                float4 w0 = *(const float4*)sb;
                float4 w1 = *(const float4*)(sb + 4);
                Bs[lk    ][lr] = w0.x; Bs[lk + 1][lr] = w0.y;
                Bs[lk + 2][lr] = w0.z; Bs[lk + 3][lr] = w0.w;
                Bs[lk + 4][lr] = w1.x; Bs[lk + 5][lr] = w1.y;
                Bs[lk + 6][lr] = w1.z; Bs[lk + 7][lr] = w1.w;
            }
        }
        __syncthreads();
        {
            float (*Bp)[132] = diag ? As : Bs;
#pragma unroll
            for (int k = 0; k < 32; k++) {
                float4 a0 = *(const float4*)&As[k][ty * 4];
                float4 b0 = *(const float4*)&Bp[k][tx * 8];
                float4 b1 = *(const float4*)&Bp[k][tx * 8 + 4];
                float aa[4] = {a0.x, a0.y, a0.z, a0.w};
                float bb[8] = {b0.x, b0.y, b0.z, b0.w, b1.x, b1.y, b1.z, b1.w};
#pragma unroll
                for (int i = 0; i < 4; i++)
#pragma unroll
                    for (int j = 0; j < 8; j++) acc[i][j] += aa[i] * bb[j];
            }
        }
        __syncthreads();
    }
#pragma unroll
    for (int i = 0; i < 4; i++) {
        int r = bi + ty * 4 + i;
        float* dst = A + (long)r * 1024 + bj + tx * 8;
        if (!diag) {
            float4 p0 = *(const float4*)dst;
            float4 p1 = *(const float4*)(dst + 4);
            p0.x -= acc[i][0]; p0.y -= acc[i][1]; p0.z -= acc[i][2]; p0.w -= acc[i][3];
            p1.x -= acc[i][4]; p1.y -= acc[i][5]; p1.z -= acc[i][6]; p1.w -= acc[i][7];
            *(float4*)dst = p0;
            *(float4*)(dst + 4) = p1;
        } else {
#pragma unroll
            for (int j = 0; j < 8; j++) {
                int c = bj + tx * 8 + j;
                if (c <= r) dst[j] -= acc[i][j];
            }
        }
    }
}

// ---------------- zupd body: z_m -= L21_m(panel s-1) @ y_{s-1} -----------------
// L21 from global (exact trsmg store), kk ascending, single RMW subtract.
__device__ void zupd_body(const float* __restrict__ C, float* __restrict__ V,
                          float* smem, int o1, int m, int b) {
    const float* A = C + (long)b * 1048576;
    float* Vp = V + (long)b * 8192;
    float (*Lb)[129] = (float(*)[129])smem;
    float (*ys)[9]   = (float(*)[9])(smem + 16512);
    int tid = threadIdx.x;
    int o0 = o1 - 128;
    {
        int kk = tid >> 2, cc = (tid & 3) * 2;
        float2 v = *(const float2*)&Vp[(o0 + kk) * 8 + cc];
        ys[kk][cc] = v.x; ys[kk][cc + 1] = v.y;
    }
#pragma unroll
    for (int mm = 0; mm < 8; mm++) {
        int e = tid + mm * 512;
        int i = e >> 5, j4 = (e & 31) * 4;
        float4 v = *(const float4*)&A[(long)(m * 128 + i) * 1024 + o0 + j4];
        Lb[i][j4] = v.x; Lb[i][j4+1] = v.y; Lb[i][j4+2] = v.z; Lb[i][j4+3] = v.w;
    }
    __syncthreads();
    int r = tid & 127, c2 = (tid >> 7) * 2;
    float u0 = 0, u1 = 0;
#pragma unroll 8
    for (int kk = 0; kk < 128; kk++) {
        float l = Lb[r][kk];
        u0 += l * ys[kk][c2];
        u1 += l * ys[kk][c2 + 1];
    }
    float* vp = &Vp[(m * 128 + r) * 8 + c2];
    float2 old = *(const float2*)vp;
    old.x -= u0; old.y -= u1;
    *(float2*)vp = old;
}

// ---------------- fused launch: potf(s) [blocks 0-15] + syrk(s-1) pairs
// (except (0,0) -> potf prologue) + zupd riders (panel s-1 -> z_m, m=s+1..7) ---
__global__ __launch_bounds__(512) void k_potf_syrk(float* __restrict__ C,
                                                   float* __restrict__ V,
                                                   int o, int last, int nsy) {
    __shared__ __align__(16) float smem[32000];   // potf 128KB; syrk 33KB; zupd 69KB
    int bx = blockIdx.x;
    if (bx < 16) {
        potf_body(C, V, smem, o, last, bx);
    } else if (bx < 16 + nsy) {
        int v = bx - 16;
        int bb = v & 15;
        int p = (v >> 4) + 1;             // skip pair (0,0)
        int tii = row_of(p);
        int tjj = p - tii * (tii + 1) / 2;
        syrk_body(C, smem, o - 128, tii, tjj, bb);
    } else {
        int v = bx - 16 - nsy;
        int bb = v & 15;
        int zj = v >> 4;
        int m = (o >> 7) + 1 + zj;        // m = s+1..7 (panel s-1)
        zupd_body(C, V, smem, o, m, bb);
    }
}

// ---------------- TRSM-GEMM, 512 threads; block 0 also updates z_{s+1} ---------
__global__ __launch_bounds__(512) void k_trsmg(float* __restrict__ C,
                                               float* __restrict__ V, int o) {
    int b = blockIdx.y;
    float* A = C + (long)b * 1048576;
    float* Vp = V + (long)b * 8192;
    int bi = o + 128 + blockIdx.x * 128;
    const float* Linv = A + (long)o * 1024 + o;
    __shared__ float As[32][132];
    __shared__ float Ls[32][132];   // block 0 reuses as ys (flat) in the tail
    int tid = threadIdx.x;
    int tx = tid & 15, ty = tid >> 4;       // ty 0..31
    float acc[4][8] = {};
    int lr = tid >> 2;
    int lk = (tid & 3) * 8;
    for (int kc = 0; kc < 128; kc += 32) {
        {
            const float* src = A + (long)(bi + lr) * 1024 + o + kc + lk;
            const float* sl  = Linv + (long)lr * 1024 + kc + lk;
            float4 v0 = *(const float4*)src;
            float4 v1 = *(const float4*)(src + 4);
            As[lk    ][lr] = v0.x; As[lk + 1][lr] = v0.y;
            As[lk + 2][lr] = v0.z; As[lk + 3][lr] = v0.w;
            As[lk + 4][lr] = v1.x; As[lk + 5][lr] = v1.y;
            As[lk + 6][lr] = v1.z; As[lk + 7][lr] = v1.w;
            float4 w0 = *(const float4*)sl;
            float4 w1 = *(const float4*)(sl + 4);
            Ls[lk    ][lr] = w0.x; Ls[lk + 1][lr] = w0.y;
            Ls[lk + 2][lr] = w0.z; Ls[lk + 3][lr] = w0.w;
            Ls[lk + 4][lr] = w1.x; Ls[lk + 5][lr] = w1.y;
            Ls[lk + 6][lr] = w1.z; Ls[lk + 7][lr] = w1.w;
        }
        __syncthreads();
#pragma unroll
        for (int k = 0; k < 32; k++) {
            float4 a0 = *(const float4*)&As[k][ty * 4];
            float4 b0 = *(const float4*)&Ls[k][tx * 8];
            float4 b1 = *(const float4*)&Ls[k][tx * 8 + 4];
            float aa[4] = {a0.x, a0.y, a0.z, a0.w};
            float bb[8] = {b0.x, b0.y, b0.z, b0.w, b1.x, b1.y, b1.z, b1.w};
#pragma unroll
            for (int i = 0; i < 4; i++)
#pragma unroll
                for (int j = 0; j < 8; j++) acc[i][j] += aa[i] * bb[j];
        }
        __syncthreads();
    }
#pragma unroll
    for (int i = 0; i < 4; i++) {
        float* dst = A + (long)(bi + ty * 4 + i) * 1024 + o + tx * 8;
        *(float4*)dst       = make_float4(acc[i][0], acc[i][1], acc[i][2], acc[i][3]);
        *(float4*)(dst + 4) = make_float4(acc[i][4], acc[i][5], acc[i][6], acc[i][7]);
    }
    if (blockIdx.x != 0) return;
    // tail (block 0 only): z_{s+1} -= L21(row s+1) @ y_s  (acc IS that L21)
    float* ysf = &Ls[0][0];
    {
        int k = tid >> 2, c2 = (tid & 3) * 2;
        float2 v = *(const float2*)&Vp[(o + k) * 8 + c2];
        ysf[k * 9 + c2] = v.x; ysf[k * 9 + c2 + 1] = v.y;
    }
    __syncthreads();
    float zacc0 = 0, zacc1 = 0;
    int zr = tid & 127, zc0 = (tid >> 7) * 2;
#pragma unroll
    for (int ch = 0; ch < 4; ch++) {
        if ((tx >> 2) == ch) {
            int cb = (tx & 3) * 8;
#pragma unroll
            for (int j = 0; j < 8; j++)
#pragma unroll
                for (int i = 0; i < 4; i++)
                    As[cb + j][ty * 4 + i] = acc[i][j];
        }
        __syncthreads();
#pragma unroll 8
        for (int k = 0; k < 32; k++) {
            float l = As[k][zr];
            const float* yp = &ysf[(ch * 32 + k) * 9 + zc0];
            zacc0 += l * yp[0]; zacc1 += l * yp[1];
        }
        __syncthreads();
    }
    float* vp = &Vp[(bi + zr) * 8 + zc0];
    float2 old = *(const float2*)vp;
    old.x -= zacc0; old.y -= zacc1;
    *(float2*)vp = old;
}

// ---------------- backward step k: y_j -= L_{k,j}^T x_k (j<k, parallel) --------
__global__ __launch_bounds__(512) void k_bstep(const float* __restrict__ C,
                                               float* __restrict__ V, int k) {
    int b = blockIdx.y, j = blockIdx.x, tid = threadIdx.x;
    const float* A = C + (long)b * 1048576;
    float* Vp = V + (long)b * 8192;
    __shared__ float Lb[128][129];
    __shared__ float xs[128][9];
    __shared__ float ys[128][9];
    {
        int kk = tid >> 2, c2 = (tid & 3) * 2;
        float2 v = *(const float2*)&Vp[(k * 128 + kk) * 8 + c2];
        xs[kk][c2] = v.x; xs[kk][c2 + 1] = v.y;
    }
#pragma unroll
    for (int m = 0; m < 8; m++) {
        int e = tid + m * 512;
        int i = e >> 5, j4 = (e & 31) * 4;
        float4 v = *(const float4*)&A[(long)(k * 128 + i) * 1024 + j * 128 + j4];
        Lb[i][j4] = v.x; Lb[i][j4+1] = v.y; Lb[i][j4+2] = v.z; Lb[i][j4+3] = v.w;
    }
    __syncthreads();
    int r = tid & 127, c2 = (tid >> 7) * 2;
    float u0 = 0, u1 = 0;
#pragma unroll 8
    for (int kk = 0; kk < 128; kk++) {
        float l = Lb[kk][r];
        u0 += l * xs[kk][c2];
        u1 += l * xs[kk][c2 + 1];
    }
    float* vp = &Vp[(j * 128 + r) * 8 + c2];
    float2 old = *(const float2*)vp;
    old.x -= u0; old.y -= u1;
    if (j < k - 1) {
        *(float2*)vp = old;
    } else {
        ys[r][c2] = old.x; ys[r][c2 + 1] = old.y;
        __syncthreads();
        int o = j * 128;
#pragma unroll
        for (int m = 0; m < 8; m++) {
            int e = tid + m * 512;
            int i = e >> 5, j4 = (e & 31) * 4;
            float4 v = *(const float4*)&A[(long)(o + i) * 1024 + o + j4];
            Lb[i][j4] = v.x; Lb[i][j4+1] = v.y; Lb[i][j4+2] = v.z; Lb[i][j4+3] = v.w;
        }
        __syncthreads();
        float x0 = 0, x1 = 0;
#pragma unroll 8
        for (int kk = 0; kk < 128; kk++) {
            float l = Lb[kk][r];
            x0 += l * ys[kk][c2];
            x1 += l * ys[kk][c2 + 1];
        }
        *(float2*)vp = make_float2(x0, x1);
    }
}

// ---------------- fused output: out[q,:] = sum_k exp(-d(Qs_q,Ks_k)) X[k,:] -----
__global__ void k_out(const float* __restrict__ Qs, const float* __restrict__ Ks,
                      const float* __restrict__ X, float* __restrict__ out) {
    int b = blockIdx.x >> 4;
    int qc = blockIdx.x & 15;
    int t = threadIdx.x;
    int q = t & 63, ks = t >> 6;
    __shared__ float kx[1024][3];
    __shared__ __align__(16) float xv[1024][8];
    __shared__ float red[4][64][8];
    for (int i = t; i < 3072; i += 256) kx[i / 3][i % 3] = Ks[b * 3072 + i];
    for (int i = t; i < 8192; i += 256) xv[i >> 3][i & 7] = X[b * 8192 + i];
    __syncthreads();
    int gq = b * 1024 + qc * 64 + q;
    const float* qp = Qs + (long)gq * 3;
    float qx = qp[0], qy = qp[1], qz = qp[2];
    float acc[8] = {};
    int k0 = ks * 256;
#pragma unroll 2
    for (int k = k0; k < k0 + 256; k++) {
        float dx = qx - kx[k][0], dy = qy - kx[k][1], dz = qz - kx[k][2];
        float w = __expf(-sqrtf(dx * dx + dy * dy + dz * dz + 1e-12f));
        float4 xa = *(const float4*)&xv[k][0];
        float4 xb = *(const float4*)&xv[k][4];
        acc[0] += w * xa.x; acc[1] += w * xa.y; acc[2] += w * xa.z; acc[3] += w * xa.w;
        acc[4] += w * xb.x; acc[5] += w * xb.y; acc[6] += w * xb.z; acc[7] += w * xb.w;
    }
#pragma unroll
    for (int c = 0; c < 8; c++) red[ks][q][c] = acc[c];
    __syncthreads();
    if (ks == 0) {
        float* op = out + (long)gq * 8;
#pragma unroll
        for (int c = 0; c < 8; c++)
            op[c] = red[0][q][c] + red[1][q][c] + red[2][q][c] + red[3][q][c];
    }
}

extern "C" void kernel_launch(void* const* d_in, const int* in_sizes, int n_in,
                              void* d_out, int out_size, void* d_ws, size_t ws_size,
                              hipStream_t stream) {
    const float* KEY   = (const float*)d_in[0];
    const float* VALUE = (const float*)d_in[1];
    const float* QUERY = (const float*)d_in[2];
    const float* W1w = (const float*)d_in[3];  const float* W1b = (const float*)d_in[4];
    const float* W2w = (const float*)d_in[5];  const float* W2b = (const float*)d_in[6];
    const float* W3w = (const float*)d_in[7];  const float* W3b = (const float*)d_in[8];
    const float* Wv1w = (const float*)d_in[9]; const float* Wv1b = (const float*)d_in[10];
    const float* Wv2w = (const float*)d_in[11];const float* Wv2b = (const float*)d_in[12];
    const float* Wv3w = (const float*)d_in[13];const float* Wv3b = (const float*)d_in[14];

    float* ws  = (float*)d_ws;
    float* C    = ws;                 // 16*1024*1024
    float* Ks   = C + 16777216;       // 16*1024*3
    float* Qs   = Ks + 49152;
    float* Vs   = Qs + 49152;         // 16*1024*8 (z -> y -> x in place)
    float* W2T  = Vs + 131072;
    float* Wv2T = W2T + 16384;

    float* out = (float*)d_out;

    hipLaunchKernelGGL(k_transpose, dim3(128), dim3(256), 0, stream, W2w, Wv2w, W2T, Wv2T);
    hipLaunchKernelGGL(k_mlp, dim3(2048), dim3(128), 0, stream,
                       KEY, Ks, QUERY, Qs, VALUE, Vs,
                       W1w, W1b, W2T, W2b, W3w, W3b,
                       Wv1w, Wv1b, Wv2T, Wv2b, Wv3w, Wv3b);
    hipLaunchKernelGGL(k_buildC, dim3(65536), dim3(256), 0, stream, Ks, C);

    // factorization + fused forward substitution: 2 launches per step.
    // launch s: potf(s) + syrk(s-1) pairs + zupd riders (panel s-1 -> z_m,
    // m=s+1..7). trsmg(s) block 0 additionally updates z_{s+1} (panel s).
    for (int s = 0; s < 8; s++) {
        int o = s * 128;
        int np = 0;
        if (s >= 1) { int ntp = 8 - s; np = ntp * (ntp + 1) / 2 - 1; }
        int nz = (s >= 1) ? (7 - s) : 0;
        hipLaunchKernelGGL(k_potf_syrk, dim3(16 + np * 16 + nz * 16), dim3(512), 0, stream,
                           C, Vs, o, (s == 7) ? 1 : 0, np * 16);
        int nt = 7 - s;
        if (nt > 0)
            hipLaunchKernelGGL(k_trsmg, dim3(nt, 16), dim3(512), 0, stream, C, Vs, o);
    }
    // backward substitution: parallel right-looking (x_7 done inside last potf)
    for (int k = 7; k >= 1; k--)
        hipLaunchKernelGGL(k_bstep, dim3(k, 16), dim3(512), 0, stream, C, Vs, k);

    hipLaunchKernelGGL(k_out, dim3(256), dim3(256), 0, stream, Qs, Ks, Vs, out);
}

// Round 11
// 980.091 us; speedup vs baseline: 1.0023x; 1.0023x over previous
//
#include <hip/hip_runtime.h>
#include <hip/hip_bf16.h>

// krignn2: out = C_qk @ inv(C_kk) @ (VALUE*mlp_v(VALUE))
// C_kk = exp(-dist(Ks,Ks)) + 1e-3 I,  Ks = KEY*mlp(KEY), Qs = QUERY*mlp(QUERY).
// Blocked fp32 Cholesky + inverted diag blocks + fused fwd/parallel bwd solve.
// R24: k_mlp LDS fix — R22's merged kernel allocated BOTH template
//      instantiations' __shared__ arrays (50.7KB -> 3 blocks/CU, 6 waves/CU;
//      78us at 36% VALUBusy, pure latency starvation). Now a single shared
//      buffer is passed in (branches union), and ONE hh[P][129] array serves
//      h1 then h2 (h1 dead after layer-2 k-loop; extra barrier before reuse).
//      LDS ~17KB -> 9 blocks/CU (18 waves). Math values/order unchanged.
//      Everything else = R23 verbatim (passing, absmax 0.00390625).

__device__ __forceinline__ int row_of(int e) {
    int i = (int)((sqrtf(8.0f * (float)e + 1.0f) - 1.0f) * 0.5f);
    while ((i + 1) * (i + 2) / 2 <= e) i++;
    while (i * (i + 1) / 2 > e) i--;
    return i;
}

// ---------------- transpose W2 / Wv2 (for coalesced layer-2 reads) -------------
__global__ void k_transpose(const float* __restrict__ W2, const float* __restrict__ Wv2,
                            float* __restrict__ W2T, float* __restrict__ Wv2T) {
    int tid = blockIdx.x * 256 + threadIdx.x;   // 0..32767
    int e = tid & 16383;
    int r = e >> 7, c = e & 127;
    if (tid < 16384) W2T[c * 128 + r] = W2[e];
    else             Wv2T[c * 128 + r] = Wv2[e];
}

// ---------------- MLP body (Linear->ReLU->Linear->ReLU->Linear) + scale --------
// sh layout: xs [P*DI] at sh[0..128); hh [P][129] at sh+128 (h1 then h2).
template<int DI, int P>
__device__ __forceinline__ void mlp_body(const float* __restrict__ in,
                                         float* __restrict__ out, int base,
                                         const float* __restrict__ W1,
                                         const float* __restrict__ b1,
                                         const float* __restrict__ W2T,
                                         const float* __restrict__ b2,
                                         const float* __restrict__ W3,
                                         const float* __restrict__ b3,
                                         float* __restrict__ sh) {
    float* xs = sh;                                  // [P*DI] (<=128)
    float (*hh)[129] = (float(*)[129])(sh + 128);    // [P][129]
    int t = threadIdx.x;
    for (int i = t; i < P * DI; i += 128) xs[i] = in[base * DI + i];
    __syncthreads();
    float w1r[DI];
#pragma unroll
    for (int d = 0; d < DI; d++) w1r[d] = W1[t * DI + d];
    float b1t = b1[t], b2t = b2[t];
#pragma unroll
    for (int p = 0; p < P; p++) {
        float s = b1t;
#pragma unroll
        for (int d = 0; d < DI; d++) s += w1r[d] * xs[p * DI + d];
        hh[p][t] = fmaxf(s, 0.0f);                   // h1
    }
    __syncthreads();
    float acc[P];
#pragma unroll
    for (int p = 0; p < P; p++) acc[p] = b2t;
    for (int k = 0; k < 128; k++) {
        float w = W2T[k * 128 + t];
#pragma unroll
        for (int p = 0; p < P; p++) acc[p] += w * hh[p][k];
    }
    __syncthreads();                                 // all h1 reads done
#pragma unroll
    for (int p = 0; p < P; p++) hh[p][t] = fmaxf(acc[p], 0.0f);   // h2 (reuse)
    __syncthreads();
    if (t < P * DI) {
        int p = t / DI, d = t % DI;
        float s = b3[d];
        for (int k = 0; k < 128; k++) s += W3[d * 128 + k] * hh[p][k];
        int gi = base * DI + t;
        out[gi] = in[gi] * s;
    }
}

// merged: blocks 0-511 KEY, 512-1023 QUERY, 1024-2047 VALUE
__global__ __launch_bounds__(128) void k_mlp(
                      const float* __restrict__ KEY, float* __restrict__ Ks,
                      const float* __restrict__ QUERY, float* __restrict__ Qs,
                      const float* __restrict__ VALUE, float* __restrict__ Vs,
                      const float* __restrict__ W1, const float* __restrict__ b1,
                      const float* __restrict__ W2T, const float* __restrict__ b2,
                      const float* __restrict__ W3, const float* __restrict__ b3,
                      const float* __restrict__ Wv1, const float* __restrict__ bv1,
                      const float* __restrict__ Wv2T, const float* __restrict__ bv2,
                      const float* __restrict__ Wv3, const float* __restrict__ bv3) {
    __shared__ __align__(16) float sh[128 + 32 * 129];   // 4256 floats = 17KB
    int bx = blockIdx.x;
    if (bx < 512)
        mlp_body<3, 32>(KEY, Ks, bx * 32, W1, b1, W2T, b2, W3, b3, sh);
    else if (bx < 1024)
        mlp_body<3, 32>(QUERY, Qs, (bx - 512) * 32, W1, b1, W2T, b2, W3, b3, sh);
    else
        mlp_body<8, 16>(VALUE, Vs, (bx - 1024) * 16, Wv1, bv1, Wv2T, bv2, Wv3, bv3, sh);
}

// ---------------- build C_kk = exp(-dist) + nugget*I ---------------------------
__global__ void k_buildC(const float* __restrict__ Ks, float* __restrict__ C) {
    long idx = (long)blockIdx.x * 256 + threadIdx.x;  // 16M elements
    int b = (int)(idx >> 20);
    int rem = (int)(idx & 1048575);
    int i = rem >> 10, j = rem & 1023;
    const float* a = Ks + ((long)b * 1024 + i) * 3;
    const float* bb = Ks + ((long)b * 1024 + j) * 3;
    float d0 = a[0] - bb[0], d1 = a[1] - bb[1], d2 = a[2] - bb[2];
    float dist = sqrtf(d0 * d0 + d1 * d1 + d2 * d2 + 1e-12f);
    float v = __expf(-dist);
    if (i == j) v += 1e-3f;
    C[idx] = v;
}

// ---------------- potf body, 512 threads, 4x8 half-tiles (R19 verbatim) --------
// smem layout (floats):
//   T   [0,16896)  128x132
//   cv  [16896,17920)  128x8
//   cw  [17920,18944)  128x8
//   Pn  [18944,19968)  128x8
//   St  [19968,28416)  2 x 32x132 (prologue staging; later Lc[6][32][33])
//   rsd [28416,28544)
//   Wb  [28544,30848)  2 x 32x36 (padded stride 36 -> float4-aligned)
//   zs  [30848,32000)  128x9
__device__ void potf_body(float* __restrict__ C, float* __restrict__ V,
                          float* smem, int o, int last, int b) {
    int tid = threadIdx.x;
    float* A = C + (long)b * 1048576;
    float* Vp = V + (long)b * 8192;
    float (*T)[132]      = (float(*)[132])smem;
    float (*cv)[8]       = (float(*)[8])(smem + 16896);
    float (*cw)[8]       = (float(*)[8])(smem + 17920);
    float (*Pn)[8]       = (float(*)[8])(smem + 18944);
    float (*St)[32][132] = (float(*)[32][132])(smem + 19968);
    float (*Lc)[32][33]  = (float(*)[32][33])(smem + 19968);   // aliases St (disjoint in time)
    float* rsd           = smem + 28416;
    float (*Wb)[32][36]  = (float(*)[32][36])(smem + 28544);
    float (*zs)[9]       = (float(*)[9])(smem + 30848);

    bool active = (tid < 272);
    int ti = 0, tj = 0, hh = 0;
    if (active) { int e = tid >> 1; hh = tid & 1; ti = row_of(e); tj = e - ti * (ti + 1) / 2; }
    int r0 = ti * 8 + hh * 4, c0t = tj * 8;
    int lane = tid & 63;
    int sr = tid >> 2, slk = (tid & 3) * 8;     // prologue staging coords

    // issue prologue stage chunk 0 early (overlaps Treg load)
    if (o > 0) {
        const float* sp = A + (long)(o + sr) * 1024 + (o - 128) + slk;
        float4 v0 = *(const float4*)sp;
        float4 v1 = *(const float4*)(sp + 4);
        St[0][slk    ][sr] = v0.x; St[0][slk + 1][sr] = v0.y;
        St[0][slk + 2][sr] = v0.z; St[0][slk + 3][sr] = v0.w;
        St[0][slk + 4][sr] = v1.x; St[0][slk + 5][sr] = v1.y;
        St[0][slk + 6][sr] = v1.z; St[0][slk + 7][sr] = v1.w;
    }
    // load diag block into registers (4 rows x 8 cols per thread)
    float Treg[4][8];
    if (active) {
        const float* src = A + (long)(o + r0) * 1024 + o + c0t;
#pragma unroll
        for (int i = 0; i < 4; i++) {
            float4 va = *(const float4*)(src + (long)i * 1024);
            float4 vb = *(const float4*)(src + (long)i * 1024 + 4);
            Treg[i][0] = va.x; Treg[i][1] = va.y; Treg[i][2] = va.z; Treg[i][3] = va.w;
            Treg[i][4] = vb.x; Treg[i][5] = vb.y; Treg[i][6] = vb.z; Treg[i][7] = vb.w;
        }
    }
    // ---- prologue: Treg -= Lp @ Lp^T, double-buffered staging ----
    if (o > 0) {
        for (int kc = 0; kc < 4; kc++) {
            __syncthreads();                      // St[kc&1] ready
            if (kc < 3) {                         // issue next chunk now
                const float* sp = A + (long)(o + sr) * 1024 + (o - 128) + (kc + 1) * 32 + slk;
                float4 v0 = *(const float4*)sp;
                float4 v1 = *(const float4*)(sp + 4);
                int nb = (kc + 1) & 1;
                St[nb][slk    ][sr] = v0.x; St[nb][slk + 1][sr] = v0.y;
                St[nb][slk + 2][sr] = v0.z; St[nb][slk + 3][sr] = v0.w;
                St[nb][slk + 4][sr] = v1.x; St[nb][slk + 5][sr] = v1.y;
                St[nb][slk + 6][sr] = v1.z; St[nb][slk + 7][sr] = v1.w;
            }
            if (active) {
                int buf = kc & 1;
#pragma unroll 4
                for (int k = 0; k < 32; k++) {
                    float4 a0 = *(const float4*)&St[buf][k][r0];
                    float4 b0 = *(const float4*)&St[buf][k][c0t];
                    float4 b1 = *(const float4*)&St[buf][k][c0t + 4];
                    float aa[4] = {a0.x, a0.y, a0.z, a0.w};
                    float bb[8] = {b0.x, b0.y, b0.z, b0.w, b1.x, b1.y, b1.z, b1.w};
#pragma unroll
                    for (int i = 0; i < 4; i++)
#pragma unroll
                        for (int j = 0; j < 8; j++) Treg[i][j] -= aa[i] * bb[j];
                }
            }
        }
    }
    // ---- initial dump of column 0 into Pn ----
    if (active && tj == 0) {
#pragma unroll
        for (int i = 0; i < 4; i++) {
            *(float4*)&Pn[r0 + i][0] = make_float4(Treg[i][0], Treg[i][1], Treg[i][2], Treg[i][3]);
            *(float4*)&Pn[r0 + i][4] = make_float4(Treg[i][4], Treg[i][5], Treg[i][6], Treg[i][7]);
        }
    }
    __syncthreads();
    // ---- 16 rank-8 panels, 2 barriers each (R16 proven structure) ----
    for (int jbt = 0; jbt < 16; jbt++) {
        int jb = jbt * 8;
        if (tid < 64) {                           // wave-0 LDL on Pn -> cv, cw
            int r1 = lane, r2 = 64 + lane;
            float v1[8], v2[8], w1[8], w2[8];
#pragma unroll
            for (int q = 0; q < 8; q++) {
                int j = jb + q;
                int jl = j & 63;
                bool hi = (j >= 64);
                float a1 = Pn[r1][q], a2 = Pn[r2][q];
#pragma unroll
                for (int p = 0; p < 8; p++) {
                    if (p < q) {
                        float wj = __shfl(hi ? w2[p] : w1[p], jl);
                        a1 -= v1[p] * wj;
                        a2 -= v2[p] * wj;
                    }
                }
                v1[q] = a1; v2[q] = a2;
                float dj = __shfl(hi ? a2 : a1, jl);
                float dinv = 1.0f / dj;
                w1[q] = a1 * dinv; w2[q] = a2 * dinv;
            }
            *(float4*)&cv[r1][0] = make_float4(v1[0], v1[1], v1[2], v1[3]);
            *(float4*)&cv[r1][4] = make_float4(v1[4], v1[5], v1[6], v1[7]);
            *(float4*)&cv[r2][0] = make_float4(v2[0], v2[1], v2[2], v2[3]);
            *(float4*)&cv[r2][4] = make_float4(v2[4], v2[5], v2[6], v2[7]);
            *(float4*)&cw[r1][0] = make_float4(w1[0], w1[1], w1[2], w1[3]);
            *(float4*)&cw[r1][4] = make_float4(w1[4], w1[5], w1[6], w1[7]);
            *(float4*)&cw[r2][0] = make_float4(w2[0], w2[1], w2[2], w2[3]);
            *(float4*)&cw[r2][4] = make_float4(w2[4], w2[5], w2[6], w2[7]);
        }
        __syncthreads();
        if (active && tj == jbt) {                // panel owners: reload LDL column
#pragma unroll
            for (int i = 0; i < 4; i++) {
                float4 va = *(const float4*)&cv[r0 + i][0];
                float4 vb = *(const float4*)&cv[r0 + i][4];
                Treg[i][0] = va.x; Treg[i][1] = va.y; Treg[i][2] = va.z; Treg[i][3] = va.w;
                Treg[i][4] = vb.x; Treg[i][5] = vb.y; Treg[i][6] = vb.z; Treg[i][7] = vb.w;
            }
        } else if (active && tj > jbt) {          // trailing update (+ fused next dump)
#pragma unroll
            for (int h = 0; h < 2; h++) {
                float va4[4][4], wb4[8][4];
#pragma unroll
                for (int i = 0; i < 4; i++) {
                    float4 v = *(const float4*)&cv[r0 + i][h * 4];
                    va4[i][0] = v.x; va4[i][1] = v.y; va4[i][2] = v.z; va4[i][3] = v.w;
                }
#pragma unroll
                for (int j = 0; j < 8; j++) {
                    float4 v = *(const float4*)&cw[c0t + j][h * 4];
                    wb4[j][0] = v.x; wb4[j][1] = v.y; wb4[j][2] = v.z; wb4[j][3] = v.w;
                }
#pragma unroll
                for (int i = 0; i < 4; i++)
#pragma unroll
                    for (int j = 0; j < 8; j++)
                        Treg[i][j] -= va4[i][0] * wb4[j][0] + va4[i][1] * wb4[j][1]
                                    + va4[i][2] * wb4[j][2] + va4[i][3] * wb4[j][3];
            }
            if (tj == jbt + 1) {                  // next panel column -> Pn
#pragma unroll
                for (int i = 0; i < 4; i++) {
                    *(float4*)&Pn[r0 + i][0] = make_float4(Treg[i][0], Treg[i][1], Treg[i][2], Treg[i][3]);
                    *(float4*)&Pn[r0 + i][4] = make_float4(Treg[i][4], Treg[i][5], Treg[i][6], Treg[i][7]);
                }
            }
        }
        __syncthreads();
    }
    // ---- dump registers (raw LDL lower) to LDS T ----
    if (active) {
#pragma unroll
        for (int i = 0; i < 4; i++) {
            *(float4*)&T[r0 + i][c0t]     = make_float4(Treg[i][0], Treg[i][1], Treg[i][2], Treg[i][3]);
            *(float4*)&T[r0 + i][c0t + 4] = make_float4(Treg[i][4], Treg[i][5], Treg[i][6], Treg[i][7]);
        }
    }
    __syncthreads();
    // ---- LDL -> Cholesky L; ZERO upper half ----
    if (tid < 128) rsd[tid] = rsqrtf(T[tid][tid]);
    __syncthreads();
    {
        int rg = tid >> 5, cg = tid & 31;
#pragma unroll
        for (int j = 0; j < 4; j++) {
            int c = cg + 32 * j;
#pragma unroll
            for (int i = 0; i < 8; i++) {
                int r = rg * 8 + i;
                if (c <= r) T[r][c] *= rsd[c];
                else        T[r][c] = 0.0f;
            }
        }
    }
    __syncthreads();
    // ---- trtri phase 2 (waves 0..3, diag 32x32 inverses) ||
    //      snapshot of original off-diag L blocks into Lc (tid>=256) ----
    {
        int wv = tid >> 6;
        if (wv < 4 && lane < 32) {
            int d0 = wv * 32;
            int j = lane;
            float x[32];
#pragma unroll
            for (int i = 0; i < 32; i++) {
                float dinv = 1.0f / T[d0 + i][d0 + i];
                float s = 0.0f;
#pragma unroll
                for (int k = 0; k < i; k++) s += T[d0 + i][d0 + k] * x[k];
                x[i] = (i == j) ? dinv : -s * dinv;
            }
#pragma unroll
            for (int i = 0; i < 32; i++) T[d0 + i][d0 + j] = x[i];
        }
        if (tid >= 256) {
            // p = i*(i-1)/2 + kb : 0:(1,0) 1:(2,0) 2:(2,1) 3:(3,0) 4:(3,1) 5:(3,2)
            for (int idx = tid - 256; idx < 6144; idx += 256) {
                int p = idx >> 10;
                int e = idx & 1023;
                int r = e >> 5, c = e & 31;
                int i3 = (p == 0) ? 1 : (p <= 2 ? 2 : 3);
                int kb = (p == 0) ? 0 : (p <= 2 ? p - 1 : p - 3);
                Lc[p][r][c] = T[i3 * 32 + r][kb * 32 + c];
            }
        }
    }
    __syncthreads();
    // ---- trtri phase 3: two parallel teams, 3 steps, 2 barriers each. ----
    {
        int team = tid >> 8, ttid = tid & 255;
        int orr = ttid >> 3, oc = (ttid & 7) * 4;
        for (int st = 0; st < 3; st++) {
            int i3, j3;
            if (team == 0) { i3 = st + 1; j3 = 0; }
            else           { i3 = (st == 0) ? 2 : 3; j3 = (st == 2) ? 2 : 1; }
            float w0 = 0, w1 = 0, w2 = 0, w3 = 0;
            for (int kb = j3; kb < i3; kb++) {
                int p = i3 * (i3 - 1) / 2 + kb;
#pragma unroll 8
                for (int kk = 0; kk < 32; kk++) {
                    float l = Lc[p][orr][kk];
                    float4 t = *(const float4*)&T[kb * 32 + kk][j3 * 32 + oc];
                    w0 += l * t.x; w1 += l * t.y; w2 += l * t.z; w3 += l * t.w;
                }
            }
            *(float4*)&Wb[team][orr][oc] = make_float4(w0, w1, w2, w3);
            __syncthreads();
            float v0 = 0, v1 = 0, v2 = 0, v3 = 0;
#pragma unroll 8
            for (int kk = 0; kk < 32; kk++) {
                float l = T[i3 * 32 + orr][i3 * 32 + kk];
                float4 wv = *(const float4*)&Wb[team][kk][oc];
                v0 += l * wv.x; v1 += l * wv.y; v2 += l * wv.z; v3 += l * wv.w;
            }
            T[i3 * 32 + orr][j3 * 32 + oc    ] = -v0;
            T[i3 * 32 + orr][j3 * 32 + oc + 1] = -v1;
            T[i3 * 32 + orr][j3 * 32 + oc + 2] = -v2;
            T[i3 * 32 + orr][j3 * 32 + oc + 3] = -v3;
            __syncthreads();
        }
    }
    // ---- writeback Linv (exact zeros above diagonal) ----
    {
        int r = tid >> 2, c0 = (tid & 3) * 32;
        float* dst = A + (long)(o + r) * 1024 + o + c0;
#pragma unroll
        for (int k = 0; k < 8; k++) {
            int c = c0 + 4 * k;
            *(float4*)(dst + 4 * k) = make_float4(T[r][c], T[r][c + 1], T[r][c + 2], T[r][c + 3]);
        }
    }
    // ---- forward diag step: y = Linv @ z; last block also x = Linv^T y ----
    {
        int k = tid >> 2, c2 = (tid & 3) * 2;
        float2 v = *(const float2*)&Vp[(o + k) * 8 + c2];
        zs[k][c2] = v.x; zs[k][c2 + 1] = v.y;
    }
    __syncthreads();
    {
        int r = tid & 127, c2 = (tid >> 7) * 2;
        float y0 = 0, y1 = 0;
#pragma unroll 8
        for (int k = 0; k < 128; k++) {
            float l = T[r][k];
            y0 += l * zs[k][c2];
            y1 += l * zs[k][c2 + 1];
        }
        if (!last) {
            *(float2*)&Vp[(o + r) * 8 + c2] = make_float2(y0, y1);
        } else {
            __syncthreads();
            zs[r][c2] = y0; zs[r][c2 + 1] = y1;
            __syncthreads();
            float x0 = 0, x1 = 0;
#pragma unroll 8
            for (int k = 0; k < 128; k++) {
                float l = T[k][r];
                x0 += l * zs[k][c2];
                x1 += l * zs[k][c2 + 1];
            }
            *(float2*)&Vp[(o + r) * 8 + c2] = make_float2(x0, x1);
        }
    }
}

// ---------------- syrk body, 512 threads, 4x8 tiles ----------------------------
__device__ void syrk_body(float* __restrict__ C, float* smem,
                          int o, int pti, int ptj, int b) {
    float* A = C + (long)b * 1048576;
    int bi = o + 128 + pti * 128, bj = o + 128 + ptj * 128;
    float (*As)[132] = (float(*)[132])smem;
    float (*Bs)[132] = (float(*)[132])(smem + 4224);
    int tid = threadIdx.x;
    int tx = tid & 15, ty = tid >> 4;       // ty 0..31 (4-row groups)
    float acc[4][8] = {};
    int lr = tid >> 2;
    int lk = (tid & 3) * 8;
    bool diag = (bi == bj);
    for (int kc = 0; kc < 128; kc += 32) {
        {
            const float* src = A + (long)(bi + lr) * 1024 + o + kc + lk;
            float4 v0 = *(const float4*)src;
            float4 v1 = *(const float4*)(src + 4);
            As[lk    ][lr] = v0.x; As[lk + 1][lr] = v0.y;
            As[lk + 2][lr] = v0.z; As[lk + 3][lr] = v0.w;
            As[lk + 4][lr] = v1.x; As[lk + 5][lr] = v1.y;
            As[lk + 6][lr] = v1.z; As[lk + 7][lr] = v1.w;
            if (!diag) {
                const float* sb = A + (long)(bj + lr) * 1024 + o + kc + lk;
                float4 w0 = *(const float4*)sb;
                float4 w1 = *(const float4*)(sb + 4);
                Bs[lk    ][lr] = w0.x; Bs[lk + 1][lr] = w0.y;
                Bs[lk + 2][lr] = w0.z; Bs[lk + 3][lr] = w0.w;
                Bs[lk + 4][lr] = w1.x; Bs[lk + 5][lr] = w1.y;
                Bs[lk + 6][lr] = w1.z; Bs[lk + 7][lr] = w1.w;
            }
        }
        __syncthreads();
        {
            float (*Bp)[132] = diag ? As : Bs;
#pragma unroll
            for (int k = 0; k < 32; k++) {
                float4 a0 = *(const float4*)&As[k][ty * 4];
                float4 b0 = *(const float4*)&Bp[k][tx * 8];
                float4 b1 = *(const float4*)&Bp[k][tx * 8 + 4];
                float aa[4] = {a0.x, a0.y, a0.z, a0.w};
                float bb[8] = {b0.x, b0.y, b0.z, b0.w, b1.x, b1.y, b1.z, b1.w};
#pragma unroll
                for (int i = 0; i < 4; i++)
#pragma unroll
                    for (int j = 0; j < 8; j++) acc[i][j] += aa[i] * bb[j];
            }
        }
        __syncthreads();
    }
#pragma unroll
    for (int i = 0; i < 4; i++) {
        int r = bi + ty * 4 + i;
        float* dst = A + (long)r * 1024 + bj + tx * 8;
        if (!diag) {
            float4 p0 = *(const float4*)dst;
            float4 p1 = *(const float4*)(dst + 4);
            p0.x -= acc[i][0]; p0.y -= acc[i][1]; p0.z -= acc[i][2]; p0.w -= acc[i][3];
            p1.x -= acc[i][4]; p1.y -= acc[i][5]; p1.z -= acc[i][6]; p1.w -= acc[i][7];
            *(float4*)dst = p0;
            *(float4*)(dst + 4) = p1;
        } else {
#pragma unroll
            for (int j = 0; j < 8; j++) {
                int c = bj + tx * 8 + j;
                if (c <= r) dst[j] -= acc[i][j];
            }
        }
    }
}

// ---------------- zupd body: z_m -= L21_m(panel s-1) @ y_{s-1} -----------------
// L21 from global (exact trsmg store), kk ascending, single RMW subtract.
__device__ void zupd_body(const float* __restrict__ C, float* __restrict__ V,
                          float* smem, int o1, int m, int b) {
    const float* A = C + (long)b * 1048576;
    float* Vp = V + (long)b * 8192;
    float (*Lb)[129] = (float(*)[129])smem;
    float (*ys)[9]   = (float(*)[9])(smem + 16512);
    int tid = threadIdx.x;
    int o0 = o1 - 128;
    {
        int kk = tid >> 2, cc = (tid & 3) * 2;
        float2 v = *(const float2*)&Vp[(o0 + kk) * 8 + cc];
        ys[kk][cc] = v.x; ys[kk][cc + 1] = v.y;
    }
#pragma unroll
    for (int mm = 0; mm < 8; mm++) {
        int e = tid + mm * 512;
        int i = e >> 5, j4 = (e & 31) * 4;
        float4 v = *(const float4*)&A[(long)(m * 128 + i) * 1024 + o0 + j4];
        Lb[i][j4] = v.x; Lb[i][j4+1] = v.y; Lb[i][j4+2] = v.z; Lb[i][j4+3] = v.w;
    }
    __syncthreads();
    int r = tid & 127, c2 = (tid >> 7) * 2;
    float u0 = 0, u1 = 0;
#pragma unroll 8
    for (int kk = 0; kk < 128; kk++) {
        float l = Lb[r][kk];
        u0 += l * ys[kk][c2];
        u1 += l * ys[kk][c2 + 1];
    }
    float* vp = &Vp[(m * 128 + r) * 8 + c2];
    float2 old = *(const float2*)vp;
    old.x -= u0; old.y -= u1;
    *(float2*)vp = old;
}

// ---------------- fused launch: potf(s) [blocks 0-15] + syrk(s-1) pairs
// (except (0,0) -> potf prologue) + zupd riders (panel s-1 -> z_m, m=s+1..7) ---
__global__ __launch_bounds__(512) void k_potf_syrk(float* __restrict__ C,
                                                   float* __restrict__ V,
                                                   int o, int last, int nsy) {
    __shared__ __align__(16) float smem[32000];   // potf 128KB; syrk 33KB; zupd 69KB
    int bx = blockIdx.x;
    if (bx < 16) {
        potf_body(C, V, smem, o, last, bx);
    } else if (bx < 16 + nsy) {
        int v = bx - 16;
        int bb = v & 15;
        int p = (v >> 4) + 1;             // skip pair (0,0)
        int tii = row_of(p);
        int tjj = p - tii * (tii + 1) / 2;
        syrk_body(C, smem, o - 128, tii, tjj, bb);
    } else {
        int v = bx - 16 - nsy;
        int bb = v & 15;
        int zj = v >> 4;
        int m = (o >> 7) + 1 + zj;        // m = s+1..7 (panel s-1)
        zupd_body(C, V, smem, o, m, bb);
    }
}

// ---------------- TRSM-GEMM, 512 threads; block 0 also updates z_{s+1} ---------
__global__ __launch_bounds__(512) void k_trsmg(float* __restrict__ C,
                                               float* __restrict__ V, int o) {
    int b = blockIdx.y;
    float* A = C + (long)b * 1048576;
    float* Vp = V + (long)b * 8192;
    int bi = o + 128 + blockIdx.x * 128;
    const float* Linv = A + (long)o * 1024 + o;
    __shared__ float As[32][132];
    __shared__ float Ls[32][132];   // block 0 reuses as ys (flat) in the tail
    int tid = threadIdx.x;
    int tx = tid & 15, ty = tid >> 4;       // ty 0..31
    float acc[4][8] = {};
    int lr = tid >> 2;
    int lk = (tid & 3) * 8;
    for (int kc = 0; kc < 128; kc += 32) {
        {
            const float* src = A + (long)(bi + lr) * 1024 + o + kc + lk;
            const float* sl  = Linv + (long)lr * 1024 + kc + lk;
            float4 v0 = *(const float4*)src;
            float4 v1 = *(const float4*)(src + 4);
            As[lk    ][lr] = v0.x; As[lk + 1][lr] = v0.y;
            As[lk + 2][lr] = v0.z; As[lk + 3][lr] = v0.w;
            As[lk + 4][lr] = v1.x; As[lk + 5][lr] = v1.y;
            As[lk + 6][lr] = v1.z; As[lk + 7][lr] = v1.w;
            float4 w0 = *(const float4*)sl;
            float4 w1 = *(const float4*)(sl + 4);
            Ls[lk    ][lr] = w0.x; Ls[lk + 1][lr] = w0.y;
            Ls[lk + 2][lr] = w0.z; Ls[lk + 3][lr] = w0.w;
            Ls[lk + 4][lr] = w1.x; Ls[lk + 5][lr] = w1.y;
            Ls[lk + 6][lr] = w1.z; Ls[lk + 7][lr] = w1.w;
        }
        __syncthreads();
#pragma unroll
        for (int k = 0; k < 32; k++) {
            float4 a0 = *(const float4*)&As[k][ty * 4];
            float4 b0 = *(const float4*)&Ls[k][tx * 8];
            float4 b1 = *(const float4*)&Ls[k][tx * 8 + 4];
            float aa[4] = {a0.x, a0.y, a0.z, a0.w};
            float bb[8] = {b0.x, b0.y, b0.z, b0.w, b1.x, b1.y, b1.z, b1.w};
#pragma unroll
            for (int i = 0; i < 4; i++)
#pragma unroll
                for (int j = 0; j < 8; j++) acc[i][j] += aa[i] * bb[j];
        }
        __syncthreads();
    }
#pragma unroll
    for (int i = 0; i < 4; i++) {
        float* dst = A + (long)(bi + ty * 4 + i) * 1024 + o + tx * 8;
        *(float4*)dst       = make_float4(acc[i][0], acc[i][1], acc[i][2], acc[i][3]);
        *(float4*)(dst + 4) = make_float4(acc[i][4], acc[i][5], acc[i][6], acc[i][7]);
    }
    if (blockIdx.x != 0) return;
    // tail (block 0 only): z_{s+1} -= L21(row s+1) @ y_s  (acc IS that L21)
    float* ysf = &Ls[0][0];
    {
        int k = tid >> 2, c2 = (tid & 3) * 2;
        float2 v = *(const float2*)&Vp[(o + k) * 8 + c2];
        ysf[k * 9 + c2] = v.x; ysf[k * 9 + c2 + 1] = v.y;
    }
    __syncthreads();
    float zacc0 = 0, zacc1 = 0;
    int zr = tid & 127, zc0 = (tid >> 7) * 2;
#pragma unroll
    for (int ch = 0; ch < 4; ch++) {
        if ((tx >> 2) == ch) {
            int cb = (tx & 3) * 8;
#pragma unroll
            for (int j = 0; j < 8; j++)
#pragma unroll
                for (int i = 0; i < 4; i++)
                    As[cb + j][ty * 4 + i] = acc[i][j];
        }
        __syncthreads();
#pragma unroll 8
        for (int k = 0; k < 32; k++) {
            float l = As[k][zr];
            const float* yp = &ysf[(ch * 32 + k) * 9 + zc0];
            zacc0 += l * yp[0]; zacc1 += l * yp[1];
        }
        __syncthreads();
    }
    float* vp = &Vp[(bi + zr) * 8 + zc0];
    float2 old = *(const float2*)vp;
    old.x -= zacc0; old.y -= zacc1;
    *(float2*)vp = old;
}

// ---------------- backward step k: y_j -= L_{k,j}^T x_k (j<k, parallel) --------
__global__ __launch_bounds__(512) void k_bstep(const float* __restrict__ C,
                                               float* __restrict__ V, int k) {
    int b = blockIdx.y, j = blockIdx.x, tid = threadIdx.x;
    const float* A = C + (long)b * 1048576;
    float* Vp = V + (long)b * 8192;
    __shared__ float Lb[128][129];
    __shared__ float xs[128][9];
    __shared__ float ys[128][9];
    {
        int kk = tid >> 2, c2 = (tid & 3) * 2;
        float2 v = *(const float2*)&Vp[(k * 128 + kk) * 8 + c2];
        xs[kk][c2] = v.x; xs[kk][c2 + 1] = v.y;
    }
#pragma unroll
    for (int m = 0; m < 8; m++) {
        int e = tid + m * 512;
        int i = e >> 5, j4 = (e & 31) * 4;
        float4 v = *(const float4*)&A[(long)(k * 128 + i) * 1024 + j * 128 + j4];
        Lb[i][j4] = v.x; Lb[i][j4+1] = v.y; Lb[i][j4+2] = v.z; Lb[i][j4+3] = v.w;
    }
    __syncthreads();
    int r = tid & 127, c2 = (tid >> 7) * 2;
    float u0 = 0, u1 = 0;
#pragma unroll 8
    for (int kk = 0; kk < 128; kk++) {
        float l = Lb[kk][r];
        u0 += l * xs[kk][c2];
        u1 += l * xs[kk][c2 + 1];
    }
    float* vp = &Vp[(j * 128 + r) * 8 + c2];
    float2 old = *(const float2*)vp;
    old.x -= u0; old.y -= u1;
    if (j < k - 1) {
        *(float2*)vp = old;
    } else {
        ys[r][c2] = old.x; ys[r][c2 + 1] = old.y;
        __syncthreads();
        int o = j * 128;
#pragma unroll
        for (int m = 0; m < 8; m++) {
            int e = tid + m * 512;
            int i = e >> 5, j4 = (e & 31) * 4;
            float4 v = *(const float4*)&A[(long)(o + i) * 1024 + o + j4];
            Lb[i][j4] = v.x; Lb[i][j4+1] = v.y; Lb[i][j4+2] = v.z; Lb[i][j4+3] = v.w;
        }
        __syncthreads();
        float x0 = 0, x1 = 0;
#pragma unroll 8
        for (int kk = 0; kk < 128; kk++) {
            float l = Lb[kk][r];
            x0 += l * ys[kk][c2];
            x1 += l * ys[kk][c2 + 1];
        }
        *(float2*)vp = make_float2(x0, x1);
    }
}

// ---------------- fused output: out[q,:] = sum_k exp(-d(Qs_q,Ks_k)) X[k,:] -----
__global__ void k_out(const float* __restrict__ Qs, const float* __restrict__ Ks,
                      const float* __restrict__ X, float* __restrict__ out) {
    int b = blockIdx.x >> 4;
    int qc = blockIdx.x & 15;
    int t = threadIdx.x;
    int q = t & 63, ks = t >> 6;
    __shared__ float kx[1024][3];
    __shared__ __align__(16) float xv[1024][8];
    __shared__ float red[4][64][8];
    for (int i = t; i < 3072; i += 256) kx[i / 3][i % 3] = Ks[b * 3072 + i];
    for (int i = t; i < 8192; i += 256) xv[i >> 3][i & 7] = X[b * 8192 + i];
    __syncthreads();
    int gq = b * 1024 + qc * 64 + q;
    const float* qp = Qs + (long)gq * 3;
    float qx = qp[0], qy = qp[1], qz = qp[2];
    float acc[8] = {};
    int k0 = ks * 256;
#pragma unroll 2
    for (int k = k0; k < k0 + 256; k++) {
        float dx = qx - kx[k][0], dy = qy - kx[k][1], dz = qz - kx[k][2];
        float w = __expf(-sqrtf(dx * dx + dy * dy + dz * dz + 1e-12f));
        float4 xa = *(const float4*)&xv[k][0];
        float4 xb = *(const float4*)&xv[k][4];
        acc[0] += w * xa.x; acc[1] += w * xa.y; acc[2] += w * xa.z; acc[3] += w * xa.w;
        acc[4] += w * xb.x; acc[5] += w * xb.y; acc[6] += w * xb.z; acc[7] += w * xb.w;
    }
#pragma unroll
    for (int c = 0; c < 8; c++) red[ks][q][c] = acc[c];
    __syncthreads();
    if (ks == 0) {
        float* op = out + (long)gq * 8;
#pragma unroll
        for (int c = 0; c < 8; c++)
            op[c] = red[0][q][c] + red[1][q][c] + red[2][q][c] + red[3][q][c];
    }
}

extern "C" void kernel_launch(void* const* d_in, const int* in_sizes, int n_in,
                              void* d_out, int out_size, void* d_ws, size_t ws_size,
                              hipStream_t stream) {
    const float* KEY   = (const float*)d_in[0];
    const float* VALUE = (const float*)d_in[1];
    const float* QUERY = (const float*)d_in[2];
    const float* W1w = (const float*)d_in[3];  const float* W1b = (const float*)d_in[4];
    const float* W2w = (const float*)d_in[5];  const float* W2b = (const float*)d_in[6];
    const float* W3w = (const float*)d_in[7];  const float* W3b = (const float*)d_in[8];
    const float* Wv1w = (const float*)d_in[9]; const float* Wv1b = (const float*)d_in[10];
    const float* Wv2w = (const float*)d_in[11];const float* Wv2b = (const float*)d_in[12];
    const float* Wv3w = (const float*)d_in[13];const float* Wv3b = (const float*)d_in[14];

    float* ws  = (float*)d_ws;
    float* C    = ws;                 // 16*1024*1024
    float* Ks   = C + 16777216;       // 16*1024*3
    float* Qs   = Ks + 49152;
    float* Vs   = Qs + 49152;         // 16*1024*8 (z -> y -> x in place)
    float* W2T  = Vs + 131072;
    float* Wv2T = W2T + 16384;

    float* out = (float*)d_out;

    hipLaunchKernelGGL(k_transpose, dim3(128), dim3(256), 0, stream, W2w, Wv2w, W2T, Wv2T);
    hipLaunchKernelGGL(k_mlp, dim3(2048), dim3(128), 0, stream,
                       KEY, Ks, QUERY, Qs, VALUE, Vs,
                       W1w, W1b, W2T, W2b, W3w, W3b,
                       Wv1w, Wv1b, Wv2T, Wv2b, Wv3w, Wv3b);
    hipLaunchKernelGGL(k_buildC, dim3(65536), dim3(256), 0, stream, Ks, C);

    // factorization + fused forward substitution: 2 launches per step.
    // launch s: potf(s) + syrk(s-1) pairs + zupd riders (panel s-1 -> z_m,
    // m=s+1..7). trsmg(s) block 0 additionally updates z_{s+1} (panel s).
    for (int s = 0; s < 8; s++) {
        int o = s * 128;
        int np = 0;
        if (s >= 1) { int ntp = 8 - s; np = ntp * (ntp + 1) / 2 - 1; }
        int nz = (s >= 1) ? (7 - s) : 0;
        hipLaunchKernelGGL(k_potf_syrk, dim3(16 + np * 16 + nz * 16), dim3(512), 0, stream,
                           C, Vs, o, (s == 7) ? 1 : 0, np * 16);
        int nt = 7 - s;
        if (nt > 0)
            hipLaunchKernelGGL(k_trsmg, dim3(nt, 16), dim3(512), 0, stream, C, Vs, o);
    }
    // backward substitution: parallel right-looking (x_7 done inside last potf)
    for (int k = 7; k >= 1; k--)
        hipLaunchKernelGGL(k_bstep, dim3(k, 16), dim3(512), 0, stream, C, Vs, k);

    hipLaunchKernelGGL(k_out, dim3(256), dim3(256), 0, stream, Qs, Ks, Vs, out);
}

// Round 12
// 954.768 us; speedup vs baseline: 1.0289x; 1.0265x over previous
//
#include <hip/hip_runtime.h>
#include <hip/hip_bf16.h>

// krignn2: out = C_qk @ inv(C_kk) @ (VALUE*mlp_v(VALUE))
// C_kk = exp(-dist(Ks,Ks)) + 1e-3 I,  Ks = KEY*mlp(KEY), Qs = QUERY*mlp(QUERY).
// Blocked fp32 Cholesky + inverted diag blocks + fused fwd/parallel bwd solve.
// R25: k_mlp is ISSUE-bound (R24: occupancy 14.5->28% with zero dur change;
//      VALUBusy 44%). Layer-2 issued 32 scalar ds_read_b32 per k (h1[p][k],
//      stride 129). Now h1 is stored K-MAJOR (h1T[128][P+4], rows 16B-aligned):
//      layer-1 computes P values into registers then writes float4s; layer-2
//      reads 8 float4 broadcasts per k (65 -> 41 instr/k, -37%) with unroll 4
//      batching the W2T loads. h2 keeps the p-major [P][129] layout (aliases
//      the same buffer after the existing barrier) -> layer-3 untouched.
//      FMA order per acc[p] unchanged (p asc within k asc) -> bit-identical.
//      Everything else = R24 verbatim (passing, absmax 0.00390625).

__device__ __forceinline__ int row_of(int e) {
    int i = (int)((sqrtf(8.0f * (float)e + 1.0f) - 1.0f) * 0.5f);
    while ((i + 1) * (i + 2) / 2 <= e) i++;
    while (i * (i + 1) / 2 > e) i--;
    return i;
}

// ---------------- transpose W2 / Wv2 (for coalesced layer-2 reads) -------------
__global__ void k_transpose(const float* __restrict__ W2, const float* __restrict__ Wv2,
                            float* __restrict__ W2T, float* __restrict__ Wv2T) {
    int tid = blockIdx.x * 256 + threadIdx.x;   // 0..32767
    int e = tid & 16383;
    int r = e >> 7, c = e & 127;
    if (tid < 16384) W2T[c * 128 + r] = W2[e];
    else             Wv2T[c * 128 + r] = Wv2[e];
}

// ---------------- MLP body (Linear->ReLU->Linear->ReLU->Linear) + scale --------
// sh layout: xs [P*DI] at sh[0..128); then h1T[128][P+4] (k-major, layer-1/2)
// aliased with h2[P][129] (p-major, layer-3). Barrier-separated reuse.
template<int DI, int P>
__device__ __forceinline__ void mlp_body(const float* __restrict__ in,
                                         float* __restrict__ out, int base,
                                         const float* __restrict__ W1,
                                         const float* __restrict__ b1,
                                         const float* __restrict__ W2T,
                                         const float* __restrict__ b2,
                                         const float* __restrict__ W3,
                                         const float* __restrict__ b3,
                                         float* __restrict__ sh) {
    constexpr int S1 = P + 4;                        // h1T row stride (16B-aligned)
    float* xs = sh;                                  // [P*DI] (<=128)
    float (*h1T)[S1] = (float(*)[S1])(sh + 128);     // [128][S1] k-major
    float (*h2)[129] = (float(*)[129])(sh + 128);    // [P][129] p-major (aliases h1T)
    int t = threadIdx.x;
    for (int i = t; i < P * DI; i += 128) xs[i] = in[base * DI + i];
    __syncthreads();
    float w1r[DI];
#pragma unroll
    for (int d = 0; d < DI; d++) w1r[d] = W1[t * DI + d];
    float b1t = b1[t], b2t = b2[t];
    float sp[P];
#pragma unroll
    for (int p = 0; p < P; p++) {
        float s = b1t;
#pragma unroll
        for (int d = 0; d < DI; d++) s += w1r[d] * xs[p * DI + d];
        sp[p] = fmaxf(s, 0.0f);
    }
#pragma unroll
    for (int p4 = 0; p4 < P; p4 += 4)
        *(float4*)&h1T[t][p4] = make_float4(sp[p4], sp[p4 + 1], sp[p4 + 2], sp[p4 + 3]);
    __syncthreads();
    float acc[P];
#pragma unroll
    for (int p = 0; p < P; p++) acc[p] = b2t;
#pragma unroll 4
    for (int k = 0; k < 128; k++) {
        float w = W2T[k * 128 + t];
#pragma unroll
        for (int p4 = 0; p4 < P; p4 += 4) {
            float4 h = *(const float4*)&h1T[k][p4];
            acc[p4    ] += w * h.x;
            acc[p4 + 1] += w * h.y;
            acc[p4 + 2] += w * h.z;
            acc[p4 + 3] += w * h.w;
        }
    }
    __syncthreads();                                 // all h1T reads done
#pragma unroll
    for (int p = 0; p < P; p++) h2[p][t] = fmaxf(acc[p], 0.0f);   // h2 (reuse)
    __syncthreads();
    if (t < P * DI) {
        int p = t / DI, d = t % DI;
        float s = b3[d];
        for (int k = 0; k < 128; k++) s += W3[d * 128 + k] * h2[p][k];
        int gi = base * DI + t;
        out[gi] = in[gi] * s;
    }
}

// merged: blocks 0-511 KEY, 512-1023 QUERY, 1024-2047 VALUE
__global__ __launch_bounds__(128) void k_mlp(
                      const float* __restrict__ KEY, float* __restrict__ Ks,
                      const float* __restrict__ QUERY, float* __restrict__ Qs,
                      const float* __restrict__ VALUE, float* __restrict__ Vs,
                      const float* __restrict__ W1, const float* __restrict__ b1,
                      const float* __restrict__ W2T, const float* __restrict__ b2,
                      const float* __restrict__ W3, const float* __restrict__ b3,
                      const float* __restrict__ Wv1, const float* __restrict__ bv1,
                      const float* __restrict__ Wv2T, const float* __restrict__ bv2,
                      const float* __restrict__ Wv3, const float* __restrict__ bv3) {
    __shared__ __align__(16) float sh[128 + 128 * 36];   // 4736 floats = 18.9KB
    int bx = blockIdx.x;
    if (bx < 512)
        mlp_body<3, 32>(KEY, Ks, bx * 32, W1, b1, W2T, b2, W3, b3, sh);
    else if (bx < 1024)
        mlp_body<3, 32>(QUERY, Qs, (bx - 512) * 32, W1, b1, W2T, b2, W3, b3, sh);
    else
        mlp_body<8, 16>(VALUE, Vs, (bx - 1024) * 16, Wv1, bv1, Wv2T, bv2, Wv3, bv3, sh);
}

// ---------------- build C_kk = exp(-dist) + nugget*I ---------------------------
__global__ void k_buildC(const float* __restrict__ Ks, float* __restrict__ C) {
    long idx = (long)blockIdx.x * 256 + threadIdx.x;  // 16M elements
    int b = (int)(idx >> 20);
    int rem = (int)(idx & 1048575);
    int i = rem >> 10, j = rem & 1023;
    const float* a = Ks + ((long)b * 1024 + i) * 3;
    const float* bb = Ks + ((long)b * 1024 + j) * 3;
    float d0 = a[0] - bb[0], d1 = a[1] - bb[1], d2 = a[2] - bb[2];
    float dist = sqrtf(d0 * d0 + d1 * d1 + d2 * d2 + 1e-12f);
    float v = __expf(-dist);
    if (i == j) v += 1e-3f;
    C[idx] = v;
}

// ---------------- potf body, 512 threads, 4x8 half-tiles (R19 verbatim) --------
// smem layout (floats):
//   T   [0,16896)  128x132
//   cv  [16896,17920)  128x8
//   cw  [17920,18944)  128x8
//   Pn  [18944,19968)  128x8
//   St  [19968,28416)  2 x 32x132 (prologue staging; later Lc[6][32][33])
//   rsd [28416,28544)
//   Wb  [28544,30848)  2 x 32x36 (padded stride 36 -> float4-aligned)
//   zs  [30848,32000)  128x9
__device__ void potf_body(float* __restrict__ C, float* __restrict__ V,
                          float* smem, int o, int last, int b) {
    int tid = threadIdx.x;
    float* A = C + (long)b * 1048576;
    float* Vp = V + (long)b * 8192;
    float (*T)[132]      = (float(*)[132])smem;
    float (*cv)[8]       = (float(*)[8])(smem + 16896);
    float (*cw)[8]       = (float(*)[8])(smem + 17920);
    float (*Pn)[8]       = (float(*)[8])(smem + 18944);
    float (*St)[32][132] = (float(*)[32][132])(smem + 19968);
    float (*Lc)[32][33]  = (float(*)[32][33])(smem + 19968);   // aliases St (disjoint in time)
    float* rsd           = smem + 28416;
    float (*Wb)[32][36]  = (float(*)[32][36])(smem + 28544);
    float (*zs)[9]       = (float(*)[9])(smem + 30848);

    bool active = (tid < 272);
    int ti = 0, tj = 0, hh = 0;
    if (active) { int e = tid >> 1; hh = tid & 1; ti = row_of(e); tj = e - ti * (ti + 1) / 2; }
    int r0 = ti * 8 + hh * 4, c0t = tj * 8;
    int lane = tid & 63;
    int sr = tid >> 2, slk = (tid & 3) * 8;     // prologue staging coords

    // issue prologue stage chunk 0 early (overlaps Treg load)
    if (o > 0) {
        const float* sp = A + (long)(o + sr) * 1024 + (o - 128) + slk;
        float4 v0 = *(const float4*)sp;
        float4 v1 = *(const float4*)(sp + 4);
        St[0][slk    ][sr] = v0.x; St[0][slk + 1][sr] = v0.y;
        St[0][slk + 2][sr] = v0.z; St[0][slk + 3][sr] = v0.w;
        St[0][slk + 4][sr] = v1.x; St[0][slk + 5][sr] = v1.y;
        St[0][slk + 6][sr] = v1.z; St[0][slk + 7][sr] = v1.w;
    }
    // load diag block into registers (4 rows x 8 cols per thread)
    float Treg[4][8];
    if (active) {
        const float* src = A + (long)(o + r0) * 1024 + o + c0t;
#pragma unroll
        for (int i = 0; i < 4; i++) {
            float4 va = *(const float4*)(src + (long)i * 1024);
            float4 vb = *(const float4*)(src + (long)i * 1024 + 4);
            Treg[i][0] = va.x; Treg[i][1] = va.y; Treg[i][2] = va.z; Treg[i][3] = va.w;
            Treg[i][4] = vb.x; Treg[i][5] = vb.y; Treg[i][6] = vb.z; Treg[i][7] = vb.w;
        }
    }
    // ---- prologue: Treg -= Lp @ Lp^T, double-buffered staging ----
    if (o > 0) {
        for (int kc = 0; kc < 4; kc++) {
            __syncthreads();                      // St[kc&1] ready
            if (kc < 3) {                         // issue next chunk now
                const float* sp = A + (long)(o + sr) * 1024 + (o - 128) + (kc + 1) * 32 + slk;
                float4 v0 = *(const float4*)sp;
                float4 v1 = *(const float4*)(sp + 4);
                int nb = (kc + 1) & 1;
                St[nb][slk    ][sr] = v0.x; St[nb][slk + 1][sr] = v0.y;
                St[nb][slk + 2][sr] = v0.z; St[nb][slk + 3][sr] = v0.w;
                St[nb][slk + 4][sr] = v1.x; St[nb][slk + 5][sr] = v1.y;
                St[nb][slk + 6][sr] = v1.z; St[nb][slk + 7][sr] = v1.w;
            }
            if (active) {
                int buf = kc & 1;
#pragma unroll 4
                for (int k = 0; k < 32; k++) {
                    float4 a0 = *(const float4*)&St[buf][k][r0];
                    float4 b0 = *(const float4*)&St[buf][k][c0t];
                    float4 b1 = *(const float4*)&St[buf][k][c0t + 4];
                    float aa[4] = {a0.x, a0.y, a0.z, a0.w};
                    float bb[8] = {b0.x, b0.y, b0.z, b0.w, b1.x, b1.y, b1.z, b1.w};
#pragma unroll
                    for (int i = 0; i < 4; i++)
#pragma unroll
                        for (int j = 0; j < 8; j++) Treg[i][j] -= aa[i] * bb[j];
                }
            }
        }
    }
    // ---- initial dump of column 0 into Pn ----
    if (active && tj == 0) {
#pragma unroll
        for (int i = 0; i < 4; i++) {
            *(float4*)&Pn[r0 + i][0] = make_float4(Treg[i][0], Treg[i][1], Treg[i][2], Treg[i][3]);
            *(float4*)&Pn[r0 + i][4] = make_float4(Treg[i][4], Treg[i][5], Treg[i][6], Treg[i][7]);
        }
    }
    __syncthreads();
    // ---- 16 rank-8 panels, 2 barriers each (R16 proven structure) ----
    for (int jbt = 0; jbt < 16; jbt++) {
        int jb = jbt * 8;
        if (tid < 64) {                           // wave-0 LDL on Pn -> cv, cw
            int r1 = lane, r2 = 64 + lane;
            float v1[8], v2[8], w1[8], w2[8];
#pragma unroll
            for (int q = 0; q < 8; q++) {
                int j = jb + q;
                int jl = j & 63;
                bool hi = (j >= 64);
                float a1 = Pn[r1][q], a2 = Pn[r2][q];
#pragma unroll
                for (int p = 0; p < 8; p++) {
                    if (p < q) {
                        float wj = __shfl(hi ? w2[p] : w1[p], jl);
                        a1 -= v1[p] * wj;
                        a2 -= v2[p] * wj;
                    }
                }
                v1[q] = a1; v2[q] = a2;
                float dj = __shfl(hi ? a2 : a1, jl);
                float dinv = 1.0f / dj;
                w1[q] = a1 * dinv; w2[q] = a2 * dinv;
            }
            *(float4*)&cv[r1][0] = make_float4(v1[0], v1[1], v1[2], v1[3]);
            *(float4*)&cv[r1][4] = make_float4(v1[4], v1[5], v1[6], v1[7]);
            *(float4*)&cv[r2][0] = make_float4(v2[0], v2[1], v2[2], v2[3]);
            *(float4*)&cv[r2][4] = make_float4(v2[4], v2[5], v2[6], v2[7]);
            *(float4*)&cw[r1][0] = make_float4(w1[0], w1[1], w1[2], w1[3]);
            *(float4*)&cw[r1][4] = make_float4(w1[4], w1[5], w1[6], w1[7]);
            *(float4*)&cw[r2][0] = make_float4(w2[0], w2[1], w2[2], w2[3]);
            *(float4*)&cw[r2][4] = make_float4(w2[4], w2[5], w2[6], w2[7]);
        }
        __syncthreads();
        if (active && tj == jbt) {                // panel owners: reload LDL column
#pragma unroll
            for (int i = 0; i < 4; i++) {
                float4 va = *(const float4*)&cv[r0 + i][0];
                float4 vb = *(const float4*)&cv[r0 + i][4];
                Treg[i][0] = va.x; Treg[i][1] = va.y; Treg[i][2] = va.z; Treg[i][3] = va.w;
                Treg[i][4] = vb.x; Treg[i][5] = vb.y; Treg[i][6] = vb.z; Treg[i][7] = vb.w;
            }
        } else if (active && tj > jbt) {          // trailing update (+ fused next dump)
#pragma unroll
            for (int h = 0; h < 2; h++) {
                float va4[4][4], wb4[8][4];
#pragma unroll
                for (int i = 0; i < 4; i++) {
                    float4 v = *(const float4*)&cv[r0 + i][h * 4];
                    va4[i][0] = v.x; va4[i][1] = v.y; va4[i][2] = v.z; va4[i][3] = v.w;
                }
#pragma unroll
                for (int j = 0; j < 8; j++) {
                    float4 v = *(const float4*)&cw[c0t + j][h * 4];
                    wb4[j][0] = v.x; wb4[j][1] = v.y; wb4[j][2] = v.z; wb4[j][3] = v.w;
                }
#pragma unroll
                for (int i = 0; i < 4; i++)
#pragma unroll
                    for (int j = 0; j < 8; j++)
                        Treg[i][j] -= va4[i][0] * wb4[j][0] + va4[i][1] * wb4[j][1]
                                    + va4[i][2] * wb4[j][2] + va4[i][3] * wb4[j][3];
            }
            if (tj == jbt + 1) {                  // next panel column -> Pn
#pragma unroll
                for (int i = 0; i < 4; i++) {
                    *(float4*)&Pn[r0 + i][0] = make_float4(Treg[i][0], Treg[i][1], Treg[i][2], Treg[i][3]);
                    *(float4*)&Pn[r0 + i][4] = make_float4(Treg[i][4], Treg[i][5], Treg[i][6], Treg[i][7]);
                }
            }
        }
        __syncthreads();
    }
    // ---- dump registers (raw LDL lower) to LDS T ----
    if (active) {
#pragma unroll
        for (int i = 0; i < 4; i++) {
            *(float4*)&T[r0 + i][c0t]     = make_float4(Treg[i][0], Treg[i][1], Treg[i][2], Treg[i][3]);
            *(float4*)&T[r0 + i][c0t + 4] = make_float4(Treg[i][4], Treg[i][5], Treg[i][6], Treg[i][7]);
        }
    }
    __syncthreads();
    // ---- LDL -> Cholesky L; ZERO upper half ----
    if (tid < 128) rsd[tid] = rsqrtf(T[tid][tid]);
    __syncthreads();
    {
        int rg = tid >> 5, cg = tid & 31;
#pragma unroll
        for (int j = 0; j < 4; j++) {
            int c = cg + 32 * j;
#pragma unroll
            for (int i = 0; i < 8; i++) {
                int r = rg * 8 + i;
                if (c <= r) T[r][c] *= rsd[c];
                else        T[r][c] = 0.0f;
            }
        }
    }
    __syncthreads();
    // ---- trtri phase 2 (waves 0..3, diag 32x32 inverses) ||
    //      snapshot of original off-diag L blocks into Lc (tid>=256) ----
    {
        int wv = tid >> 6;
        if (wv < 4 && lane < 32) {
            int d0 = wv * 32;
            int j = lane;
            float x[32];
#pragma unroll
            for (int i = 0; i < 32; i++) {
                float dinv = 1.0f / T[d0 + i][d0 + i];
                float s = 0.0f;
#pragma unroll
                for (int k = 0; k < i; k++) s += T[d0 + i][d0 + k] * x[k];
                x[i] = (i == j) ? dinv : -s * dinv;
            }
#pragma unroll
            for (int i = 0; i < 32; i++) T[d0 + i][d0 + j] = x[i];
        }
        if (tid >= 256) {
            // p = i*(i-1)/2 + kb : 0:(1,0) 1:(2,0) 2:(2,1) 3:(3,0) 4:(3,1) 5:(3,2)
            for (int idx = tid - 256; idx < 6144; idx += 256) {
                int p = idx >> 10;
                int e = idx & 1023;
                int r = e >> 5, c = e & 31;
                int i3 = (p == 0) ? 1 : (p <= 2 ? 2 : 3);
                int kb = (p == 0) ? 0 : (p <= 2 ? p - 1 : p - 3);
                Lc[p][r][c] = T[i3 * 32 + r][kb * 32 + c];
            }
        }
    }
    __syncthreads();
    // ---- trtri phase 3: two parallel teams, 3 steps, 2 barriers each. ----
    {
        int team = tid >> 8, ttid = tid & 255;
        int orr = ttid >> 3, oc = (ttid & 7) * 4;
        for (int st = 0; st < 3; st++) {
            int i3, j3;
            if (team == 0) { i3 = st + 1; j3 = 0; }
            else           { i3 = (st == 0) ? 2 : 3; j3 = (st == 2) ? 2 : 1; }
            float w0 = 0, w1 = 0, w2 = 0, w3 = 0;
            for (int kb = j3; kb < i3; kb++) {
                int p = i3 * (i3 - 1) / 2 + kb;
#pragma unroll 8
                for (int kk = 0; kk < 32; kk++) {
                    float l = Lc[p][orr][kk];
                    float4 t = *(const float4*)&T[kb * 32 + kk][j3 * 32 + oc];
                    w0 += l * t.x; w1 += l * t.y; w2 += l * t.z; w3 += l * t.w;
                }
            }
            *(float4*)&Wb[team][orr][oc] = make_float4(w0, w1, w2, w3);
            __syncthreads();
            float v0 = 0, v1 = 0, v2 = 0, v3 = 0;
#pragma unroll 8
            for (int kk = 0; kk < 32; kk++) {
                float l = T[i3 * 32 + orr][i3 * 32 + kk];
                float4 wv = *(const float4*)&Wb[team][kk][oc];
                v0 += l * wv.x; v1 += l * wv.y; v2 += l * wv.z; v3 += l * wv.w;
            }
            T[i3 * 32 + orr][j3 * 32 + oc    ] = -v0;
            T[i3 * 32 + orr][j3 * 32 + oc + 1] = -v1;
            T[i3 * 32 + orr][j3 * 32 + oc + 2] = -v2;
            T[i3 * 32 + orr][j3 * 32 + oc + 3] = -v3;
            __syncthreads();
        }
    }
    // ---- writeback Linv (exact zeros above diagonal) ----
    {
        int r = tid >> 2, c0 = (tid & 3) * 32;
        float* dst = A + (long)(o + r) * 1024 + o + c0;
#pragma unroll
        for (int k = 0; k < 8; k++) {
            int c = c0 + 4 * k;
            *(float4*)(dst + 4 * k) = make_float4(T[r][c], T[r][c + 1], T[r][c + 2], T[r][c + 3]);
        }
    }
    // ---- forward diag step: y = Linv @ z; last block also x = Linv^T y ----
    {
        int k = tid >> 2, c2 = (tid & 3) * 2;
        float2 v = *(const float2*)&Vp[(o + k) * 8 + c2];
        zs[k][c2] = v.x; zs[k][c2 + 1] = v.y;
    }
    __syncthreads();
    {
        int r = tid & 127, c2 = (tid >> 7) * 2;
        float y0 = 0, y1 = 0;
#pragma unroll 8
        for (int k = 0; k < 128; k++) {
            float l = T[r][k];
            y0 += l * zs[k][c2];
            y1 += l * zs[k][c2 + 1];
        }
        if (!last) {
            *(float2*)&Vp[(o + r) * 8 + c2] = make_float2(y0, y1);
        } else {
            __syncthreads();
            zs[r][c2] = y0; zs[r][c2 + 1] = y1;
            __syncthreads();
            float x0 = 0, x1 = 0;
#pragma unroll 8
            for (int k = 0; k < 128; k++) {
                float l = T[k][r];
                x0 += l * zs[k][c2];
                x1 += l * zs[k][c2 + 1];
            }
            *(float2*)&Vp[(o + r) * 8 + c2] = make_float2(x0, x1);
        }
    }
}

// ---------------- syrk body, 512 threads, 4x8 tiles ----------------------------
__device__ void syrk_body(float* __restrict__ C, float* smem,
                          int o, int pti, int ptj, int b) {
    float* A = C + (long)b * 1048576;
    int bi = o + 128 + pti * 128, bj = o + 128 + ptj * 128;
    float (*As)[132] = (float(*)[132])smem;
    float (*Bs)[132] = (float(*)[132])(smem + 4224);
    int tid = threadIdx.x;
    int tx = tid & 15, ty = tid >> 4;       // ty 0..31 (4-row groups)
    float acc[4][8] = {};
    int lr = tid >> 2;
    int lk = (tid & 3) * 8;
    bool diag = (bi == bj);
    for (int kc = 0; kc < 128; kc += 32) {
        {
            const float* src = A + (long)(bi + lr) * 1024 + o + kc + lk;
            float4 v0 = *(const float4*)src;
            float4 v1 = *(const float4*)(src + 4);
            As[lk    ][lr] = v0.x; As[lk + 1][lr] = v0.y;
            As[lk + 2][lr] = v0.z; As[lk + 3][lr] = v0.w;
            As[lk + 4][lr] = v1.x; As[lk + 5][lr] = v1.y;
            As[lk + 6][lr] = v1.z; As[lk + 7][lr] = v1.w;
            if (!diag) {
                const float* sb = A + (long)(bj + lr) * 1024 + o + kc + lk;
                float4 w0 = *(const float4*)sb;
                float4 w1 = *(const float4*)(sb + 4);
                Bs[lk    ][lr] = w0.x; Bs[lk + 1][lr] = w0.y;
                Bs[lk + 2][lr] = w0.z; Bs[lk + 3][lr] = w0.w;
                Bs[lk + 4][lr] = w1.x; Bs[lk + 5][lr] = w1.y;
                Bs[lk + 6][lr] = w1.z; Bs[lk + 7][lr] = w1.w;
            }
        }
        __syncthreads();
        {
            float (*Bp)[132] = diag ? As : Bs;
#pragma unroll
            for (int k = 0; k < 32; k++) {
                float4 a0 = *(const float4*)&As[k][ty * 4];
                float4 b0 = *(const float4*)&Bp[k][tx * 8];
                float4 b1 = *(const float4*)&Bp[k][tx * 8 + 4];
                float aa[4] = {a0.x, a0.y, a0.z, a0.w};
                float bb[8] = {b0.x, b0.y, b0.z, b0.w, b1.x, b1.y, b1.z, b1.w};
#pragma unroll
                for (int i = 0; i < 4; i++)
#pragma unroll
                    for (int j = 0; j < 8; j++) acc[i][j] += aa[i] * bb[j];
            }
        }
        __syncthreads();
    }
#pragma unroll
    for (int i = 0; i < 4; i++) {
        int r = bi + ty * 4 + i;
        float* dst = A + (long)r * 1024 + bj + tx * 8;
        if (!diag) {
            float4 p0 = *(const float4*)dst;
            float4 p1 = *(const float4*)(dst + 4);
            p0.x -= acc[i][0]; p0.y -= acc[i][1]; p0.z -= acc[i][2]; p0.w -= acc[i][3];
            p1.x -= acc[i][4]; p1.y -= acc[i][5]; p1.z -= acc[i][6]; p1.w -= acc[i][7];
            *(float4*)dst = p0;
            *(float4*)(dst + 4) = p1;
        } else {
#pragma unroll
            for (int j = 0; j < 8; j++) {
                int c = bj + tx * 8 + j;
                if (c <= r) dst[j] -= acc[i][j];
            }
        }
    }
}

// ---------------- zupd body: z_m -= L21_m(panel s-1) @ y_{s-1} -----------------
// L21 from global (exact trsmg store), kk ascending, single RMW subtract.
__device__ void zupd_body(const float* __restrict__ C, float* __restrict__ V,
                          float* smem, int o1, int m, int b) {
    const float* A = C + (long)b * 1048576;
    float* Vp = V + (long)b * 8192;
    float (*Lb)[129] = (float(*)[129])smem;
    float (*ys)[9]   = (float(*)[9])(smem + 16512);
    int tid = threadIdx.x;
    int o0 = o1 - 128;
    {
        int kk = tid >> 2, cc = (tid & 3) * 2;
        float2 v = *(const float2*)&Vp[(o0 + kk) * 8 + cc];
        ys[kk][cc] = v.x; ys[kk][cc + 1] = v.y;
    }
#pragma unroll
    for (int mm = 0; mm < 8; mm++) {
        int e = tid + mm * 512;
        int i = e >> 5, j4 = (e & 31) * 4;
        float4 v = *(const float4*)&A[(long)(m * 128 + i) * 1024 + o0 + j4];
        Lb[i][j4] = v.x; Lb[i][j4+1] = v.y; Lb[i][j4+2] = v.z; Lb[i][j4+3] = v.w;
    }
    __syncthreads();
    int r = tid & 127, c2 = (tid >> 7) * 2;
    float u0 = 0, u1 = 0;
#pragma unroll 8
    for (int kk = 0; kk < 128; kk++) {
        float l = Lb[r][kk];
        u0 += l * ys[kk][c2];
        u1 += l * ys[kk][c2 + 1];
    }
    float* vp = &Vp[(m * 128 + r) * 8 + c2];
    float2 old = *(const float2*)vp;
    old.x -= u0; old.y -= u1;
    *(float2*)vp = old;
}

// ---------------- fused launch: potf(s) [blocks 0-15] + syrk(s-1) pairs
// (except (0,0) -> potf prologue) + zupd riders (panel s-1 -> z_m, m=s+1..7) ---
__global__ __launch_bounds__(512) void k_potf_syrk(float* __restrict__ C,
                                                   float* __restrict__ V,
                                                   int o, int last, int nsy) {
    __shared__ __align__(16) float smem[32000];   // potf 128KB; syrk 33KB; zupd 69KB
    int bx = blockIdx.x;
    if (bx < 16) {
        potf_body(C, V, smem, o, last, bx);
    } else if (bx < 16 + nsy) {
        int v = bx - 16;
        int bb = v & 15;
        int p = (v >> 4) + 1;             // skip pair (0,0)
        int tii = row_of(p);
        int tjj = p - tii * (tii + 1) / 2;
        syrk_body(C, smem, o - 128, tii, tjj, bb);
    } else {
        int v = bx - 16 - nsy;
        int bb = v & 15;
        int zj = v >> 4;
        int m = (o >> 7) + 1 + zj;        // m = s+1..7 (panel s-1)
        zupd_body(C, V, smem, o, m, bb);
    }
}

// ---------------- TRSM-GEMM, 512 threads; block 0 also updates z_{s+1} ---------
__global__ __launch_bounds__(512) void k_trsmg(float* __restrict__ C,
                                               float* __restrict__ V, int o) {
    int b = blockIdx.y;
    float* A = C + (long)b * 1048576;
    float* Vp = V + (long)b * 8192;
    int bi = o + 128 + blockIdx.x * 128;
    const float* Linv = A + (long)o * 1024 + o;
    __shared__ float As[32][132];
    __shared__ float Ls[32][132];   // block 0 reuses as ys (flat) in the tail
    int tid = threadIdx.x;
    int tx = tid & 15, ty = tid >> 4;       // ty 0..31
    float acc[4][8] = {};
    int lr = tid >> 2;
    int lk = (tid & 3) * 8;
    for (int kc = 0; kc < 128; kc += 32) {
        {
            const float* src = A + (long)(bi + lr) * 1024 + o + kc + lk;
            const float* sl  = Linv + (long)lr * 1024 + kc + lk;
            float4 v0 = *(const float4*)src;
            float4 v1 = *(const float4*)(src + 4);
            As[lk    ][lr] = v0.x; As[lk + 1][lr] = v0.y;
            As[lk + 2][lr] = v0.z; As[lk + 3][lr] = v0.w;
            As[lk + 4][lr] = v1.x; As[lk + 5][lr] = v1.y;
            As[lk + 6][lr] = v1.z; As[lk + 7][lr] = v1.w;
            float4 w0 = *(const float4*)sl;
            float4 w1 = *(const float4*)(sl + 4);
            Ls[lk    ][lr] = w0.x; Ls[lk + 1][lr] = w0.y;
            Ls[lk + 2][lr] = w0.z; Ls[lk + 3][lr] = w0.w;
            Ls[lk + 4][lr] = w1.x; Ls[lk + 5][lr] = w1.y;
            Ls[lk + 6][lr] = w1.z; Ls[lk + 7][lr] = w1.w;
        }
        __syncthreads();
#pragma unroll
        for (int k = 0; k < 32; k++) {
            float4 a0 = *(const float4*)&As[k][ty * 4];
            float4 b0 = *(const float4*)&Ls[k][tx * 8];
            float4 b1 = *(const float4*)&Ls[k][tx * 8 + 4];
            float aa[4] = {a0.x, a0.y, a0.z, a0.w};
            float bb[8] = {b0.x, b0.y, b0.z, b0.w, b1.x, b1.y, b1.z, b1.w};
#pragma unroll
            for (int i = 0; i < 4; i++)
#pragma unroll
                for (int j = 0; j < 8; j++) acc[i][j] += aa[i] * bb[j];
        }
        __syncthreads();
    }
#pragma unroll
    for (int i = 0; i < 4; i++) {
        float* dst = A + (long)(bi + ty * 4 + i) * 1024 + o + tx * 8;
        *(float4*)dst       = make_float4(acc[i][0], acc[i][1], acc[i][2], acc[i][3]);
        *(float4*)(dst + 4) = make_float4(acc[i][4], acc[i][5], acc[i][6], acc[i][7]);
    }
    if (blockIdx.x != 0) return;
    // tail (block 0 only): z_{s+1} -= L21(row s+1) @ y_s  (acc IS that L21)
    float* ysf = &Ls[0][0];
    {
        int k = tid >> 2, c2 = (tid & 3) * 2;
        float2 v = *(const float2*)&Vp[(o + k) * 8 + c2];
        ysf[k * 9 + c2] = v.x; ysf[k * 9 + c2 + 1] = v.y;
    }
    __syncthreads();
    float zacc0 = 0, zacc1 = 0;
    int zr = tid & 127, zc0 = (tid >> 7) * 2;
#pragma unroll
    for (int ch = 0; ch < 4; ch++) {
        if ((tx >> 2) == ch) {
            int cb = (tx & 3) * 8;
#pragma unroll
            for (int j = 0; j < 8; j++)
#pragma unroll
                for (int i = 0; i < 4; i++)
                    As[cb + j][ty * 4 + i] = acc[i][j];
        }
        __syncthreads();
#pragma unroll 8
        for (int k = 0; k < 32; k++) {
            float l = As[k][zr];
            const float* yp = &ysf[(ch * 32 + k) * 9 + zc0];
            zacc0 += l * yp[0]; zacc1 += l * yp[1];
        }
        __syncthreads();
    }
    float* vp = &Vp[(bi + zr) * 8 + zc0];
    float2 old = *(const float2*)vp;
    old.x -= zacc0; old.y -= zacc1;
    *(float2*)vp = old;
}

// ---------------- backward step k: y_j -= L_{k,j}^T x_k (j<k, parallel) --------
__global__ __launch_bounds__(512) void k_bstep(const float* __restrict__ C,
                                               float* __restrict__ V, int k) {
    int b = blockIdx.y, j = blockIdx.x, tid = threadIdx.x;
    const float* A = C + (long)b * 1048576;
    float* Vp = V + (long)b * 8192;
    __shared__ float Lb[128][129];
    __shared__ float xs[128][9];
    __shared__ float ys[128][9];
    {
        int kk = tid >> 2, c2 = (tid & 3) * 2;
        float2 v = *(const float2*)&Vp[(k * 128 + kk) * 8 + c2];
        xs[kk][c2] = v.x; xs[kk][c2 + 1] = v.y;
    }
#pragma unroll
    for (int m = 0; m < 8; m++) {
        int e = tid + m * 512;
        int i = e >> 5, j4 = (e & 31) * 4;
        float4 v = *(const float4*)&A[(long)(k * 128 + i) * 1024 + j * 128 + j4];
        Lb[i][j4] = v.x; Lb[i][j4+1] = v.y; Lb[i][j4+2] = v.z; Lb[i][j4+3] = v.w;
    }
    __syncthreads();
    int r = tid & 127, c2 = (tid >> 7) * 2;
    float u0 = 0, u1 = 0;
#pragma unroll 8
    for (int kk = 0; kk < 128; kk++) {
        float l = Lb[kk][r];
        u0 += l * xs[kk][c2];
        u1 += l * xs[kk][c2 + 1];
    }
    float* vp = &Vp[(j * 128 + r) * 8 + c2];
    float2 old = *(const float2*)vp;
    old.x -= u0; old.y -= u1;
    if (j < k - 1) {
        *(float2*)vp = old;
    } else {
        ys[r][c2] = old.x; ys[r][c2 + 1] = old.y;
        __syncthreads();
        int o = j * 128;
#pragma unroll
        for (int m = 0; m < 8; m++) {
            int e = tid + m * 512;
            int i = e >> 5, j4 = (e & 31) * 4;
            float4 v = *(const float4*)&A[(long)(o + i) * 1024 + o + j4];
            Lb[i][j4] = v.x; Lb[i][j4+1] = v.y; Lb[i][j4+2] = v.z; Lb[i][j4+3] = v.w;
        }
        __syncthreads();
        float x0 = 0, x1 = 0;
#pragma unroll 8
        for (int kk = 0; kk < 128; kk++) {
            float l = Lb[kk][r];
            x0 += l * ys[kk][c2];
            x1 += l * ys[kk][c2 + 1];
        }
        *(float2*)vp = make_float2(x0, x1);
    }
}

// ---------------- fused output: out[q,:] = sum_k exp(-d(Qs_q,Ks_k)) X[k,:] -----
__global__ void k_out(const float* __restrict__ Qs, const float* __restrict__ Ks,
                      const float* __restrict__ X, float* __restrict__ out) {
    int b = blockIdx.x >> 4;
    int qc = blockIdx.x & 15;
    int t = threadIdx.x;
    int q = t & 63, ks = t >> 6;
    __shared__ float kx[1024][3];
    __shared__ __align__(16) float xv[1024][8];
    __shared__ float red[4][64][8];
    for (int i = t; i < 3072; i += 256) kx[i / 3][i % 3] = Ks[b * 3072 + i];
    for (int i = t; i < 8192; i += 256) xv[i >> 3][i & 7] = X[b * 8192 + i];
    __syncthreads();
    int gq = b * 1024 + qc * 64 + q;
    const float* qp = Qs + (long)gq * 3;
    float qx = qp[0], qy = qp[1], qz = qp[2];
    float acc[8] = {};
    int k0 = ks * 256;
#pragma unroll 2
    for (int k = k0; k < k0 + 256; k++) {
        float dx = qx - kx[k][0], dy = qy - kx[k][1], dz = qz - kx[k][2];
        float w = __expf(-sqrtf(dx * dx + dy * dy + dz * dz + 1e-12f));
        float4 xa = *(const float4*)&xv[k][0];
        float4 xb = *(const float4*)&xv[k][4];
        acc[0] += w * xa.x; acc[1] += w * xa.y; acc[2] += w * xa.z; acc[3] += w * xa.w;
        acc[4] += w * xb.x; acc[5] += w * xb.y; acc[6] += w * xb.z; acc[7] += w * xb.w;
    }
#pragma unroll
    for (int c = 0; c < 8; c++) red[ks][q][c] = acc[c];
    __syncthreads();
    if (ks == 0) {
        float* op = out + (long)gq * 8;
#pragma unroll
        for (int c = 0; c < 8; c++)
            op[c] = red[0][q][c] + red[1][q][c] + red[2][q][c] + red[3][q][c];
    }
}

extern "C" void kernel_launch(void* const* d_in, const int* in_sizes, int n_in,
                              void* d_out, int out_size, void* d_ws, size_t ws_size,
                              hipStream_t stream) {
    const float* KEY   = (const float*)d_in[0];
    const float* VALUE = (const float*)d_in[1];
    const float* QUERY = (const float*)d_in[2];
    const float* W1w = (const float*)d_in[3];  const float* W1b = (const float*)d_in[4];
    const float* W2w = (const float*)d_in[5];  const float* W2b = (const float*)d_in[6];
    const float* W3w = (const float*)d_in[7];  const float* W3b = (const float*)d_in[8];
    const float* Wv1w = (const float*)d_in[9]; const float* Wv1b = (const float*)d_in[10];
    const float* Wv2w = (const float*)d_in[11];const float* Wv2b = (const float*)d_in[12];
    const float* Wv3w = (const float*)d_in[13];const float* Wv3b = (const float*)d_in[14];

    float* ws  = (float*)d_ws;
    float* C    = ws;                 // 16*1024*1024
    float* Ks   = C + 16777216;       // 16*1024*3
    float* Qs   = Ks + 49152;
    float* Vs   = Qs + 49152;         // 16*1024*8 (z -> y -> x in place)
    float* W2T  = Vs + 131072;
    float* Wv2T = W2T + 16384;

    float* out = (float*)d_out;

    hipLaunchKernelGGL(k_transpose, dim3(128), dim3(256), 0, stream, W2w, Wv2w, W2T, Wv2T);
    hipLaunchKernelGGL(k_mlp, dim3(2048), dim3(128), 0, stream,
                       KEY, Ks, QUERY, Qs, VALUE, Vs,
                       W1w, W1b, W2T, W2b, W3w, W3b,
                       Wv1w, Wv1b, Wv2T, Wv2b, Wv3w, Wv3b);
    hipLaunchKernelGGL(k_buildC, dim3(65536), dim3(256), 0, stream, Ks, C);

    // factorization + fused forward substitution: 2 launches per step.
    // launch s: potf(s) + syrk(s-1) pairs + zupd riders (panel s-1 -> z_m,
    // m=s+1..7). trsmg(s) block 0 additionally updates z_{s+1} (panel s).
    for (int s = 0; s < 8; s++) {
        int o = s * 128;
        int np = 0;
        if (s >= 1) { int ntp = 8 - s; np = ntp * (ntp + 1) / 2 - 1; }
        int nz = (s >= 1) ? (7 - s) : 0;
        hipLaunchKernelGGL(k_potf_syrk, dim3(16 + np * 16 + nz * 16), dim3(512), 0, stream,
                           C, Vs, o, (s == 7) ? 1 : 0, np * 16);
        int nt = 7 - s;
        if (nt > 0)
            hipLaunchKernelGGL(k_trsmg, dim3(nt, 16), dim3(512), 0, stream, C, Vs, o);
    }
    // backward substitution: parallel right-looking (x_7 done inside last potf)
    for (int k = 7; k >= 1; k--)
        hipLaunchKernelGGL(k_bstep, dim3(k, 16), dim3(512), 0, stream, C, Vs, k);

    hipLaunchKernelGGL(k_out, dim3(256), dim3(256), 0, stream, Qs, Ks, Vs, out);
}

// Round 13
// 933.753 us; speedup vs baseline: 1.0520x; 1.0225x over previous
//
#include <hip/hip_runtime.h>
#include <hip/hip_bf16.h>

// krignn2: out = C_qk @ inv(C_kk) @ (VALUE*mlp_v(VALUE))
// C_kk = exp(-dist(Ks,Ks)) + 1e-3 I,  Ks = KEY*mlp(KEY), Qs = QUERY*mlp(QUERY).
// Blocked fp32 Cholesky + inverted diag blocks + fused fwd/parallel bwd solve.
// R26: buildC folded into launch 0. potf(0) builds its own 128x128 diag block
//      directly from Ks (staged in the free St region; identical sqrtf/__expf
//      expression -> bit-identical values); 240 grid-stride rider blocks on
//      the potf_syrk(0) launch build the REST of C (skipping the diag-block-0
//      elements, which potf overwrites with Linv -> disjoint, no race).
//      Riders hide (~63MB writes) under potf(0)'s ~65us. Dispatches 25->24.
//      Everything else = R25 verbatim (954.8us, passing, absmax 0.00390625).

__device__ __forceinline__ int row_of(int e) {
    int i = (int)((sqrtf(8.0f * (float)e + 1.0f) - 1.0f) * 0.5f);
    while ((i + 1) * (i + 2) / 2 <= e) i++;
    while (i * (i + 1) / 2 > e) i--;
    return i;
}

// ---------------- transpose W2 / Wv2 (for coalesced layer-2 reads) -------------
__global__ void k_transpose(const float* __restrict__ W2, const float* __restrict__ Wv2,
                            float* __restrict__ W2T, float* __restrict__ Wv2T) {
    int tid = blockIdx.x * 256 + threadIdx.x;   // 0..32767
    int e = tid & 16383;
    int r = e >> 7, c = e & 127;
    if (tid < 16384) W2T[c * 128 + r] = W2[e];
    else             Wv2T[c * 128 + r] = Wv2[e];
}

// ---------------- MLP body (Linear->ReLU->Linear->ReLU->Linear) + scale --------
// sh layout: xs [P*DI] at sh[0..128); then h1T[128][P+4] (k-major, layer-1/2)
// aliased with h2[P][129] (p-major, layer-3). Barrier-separated reuse.
template<int DI, int P>
__device__ __forceinline__ void mlp_body(const float* __restrict__ in,
                                         float* __restrict__ out, int base,
                                         const float* __restrict__ W1,
                                         const float* __restrict__ b1,
                                         const float* __restrict__ W2T,
                                         const float* __restrict__ b2,
                                         const float* __restrict__ W3,
                                         const float* __restrict__ b3,
                                         float* __restrict__ sh) {
    constexpr int S1 = P + 4;                        // h1T row stride (16B-aligned)
    float* xs = sh;                                  // [P*DI] (<=128)
    float (*h1T)[S1] = (float(*)[S1])(sh + 128);     // [128][S1] k-major
    float (*h2)[129] = (float(*)[129])(sh + 128);    // [P][129] p-major (aliases h1T)
    int t = threadIdx.x;
    for (int i = t; i < P * DI; i += 128) xs[i] = in[base * DI + i];
    __syncthreads();
    float w1r[DI];
#pragma unroll
    for (int d = 0; d < DI; d++) w1r[d] = W1[t * DI + d];
    float b1t = b1[t], b2t = b2[t];
    float sp[P];
#pragma unroll
    for (int p = 0; p < P; p++) {
        float s = b1t;
#pragma unroll
        for (int d = 0; d < DI; d++) s += w1r[d] * xs[p * DI + d];
        sp[p] = fmaxf(s, 0.0f);
    }
#pragma unroll
    for (int p4 = 0; p4 < P; p4 += 4)
        *(float4*)&h1T[t][p4] = make_float4(sp[p4], sp[p4 + 1], sp[p4 + 2], sp[p4 + 3]);
    __syncthreads();
    float acc[P];
#pragma unroll
    for (int p = 0; p < P; p++) acc[p] = b2t;
#pragma unroll 4
    for (int k = 0; k < 128; k++) {
        float w = W2T[k * 128 + t];
#pragma unroll
        for (int p4 = 0; p4 < P; p4 += 4) {
            float4 h = *(const float4*)&h1T[k][p4];
            acc[p4    ] += w * h.x;
            acc[p4 + 1] += w * h.y;
            acc[p4 + 2] += w * h.z;
            acc[p4 + 3] += w * h.w;
        }
    }
    __syncthreads();                                 // all h1T reads done
#pragma unroll
    for (int p = 0; p < P; p++) h2[p][t] = fmaxf(acc[p], 0.0f);   // h2 (reuse)
    __syncthreads();
    if (t < P * DI) {
        int p = t / DI, d = t % DI;
        float s = b3[d];
        for (int k = 0; k < 128; k++) s += W3[d * 128 + k] * h2[p][k];
        int gi = base * DI + t;
        out[gi] = in[gi] * s;
    }
}

// merged: blocks 0-511 KEY, 512-1023 QUERY, 1024-2047 VALUE
__global__ __launch_bounds__(128) void k_mlp(
                      const float* __restrict__ KEY, float* __restrict__ Ks,
                      const float* __restrict__ QUERY, float* __restrict__ Qs,
                      const float* __restrict__ VALUE, float* __restrict__ Vs,
                      const float* __restrict__ W1, const float* __restrict__ b1,
                      const float* __restrict__ W2T, const float* __restrict__ b2,
                      const float* __restrict__ W3, const float* __restrict__ b3,
                      const float* __restrict__ Wv1, const float* __restrict__ bv1,
                      const float* __restrict__ Wv2T, const float* __restrict__ bv2,
                      const float* __restrict__ Wv3, const float* __restrict__ bv3) {
    __shared__ __align__(16) float sh[128 + 128 * 36];   // 4736 floats = 18.9KB
    int bx = blockIdx.x;
    if (bx < 512)
        mlp_body<3, 32>(KEY, Ks, bx * 32, W1, b1, W2T, b2, W3, b3, sh);
    else if (bx < 1024)
        mlp_body<3, 32>(QUERY, Qs, (bx - 512) * 32, W1, b1, W2T, b2, W3, b3, sh);
    else
        mlp_body<8, 16>(VALUE, Vs, (bx - 1024) * 16, Wv1, bv1, Wv2T, bv2, Wv3, bv3, sh);
}

// ---------------- buildC rider: C = exp(-dist) + nugget*I (skip diag block 0) --
// Identical expression to the old k_buildC -> bit-identical values.
__device__ void buildc_rider(const float* __restrict__ Ks, float* __restrict__ C,
                             int rid, int nrid) {
    const long total = 16777216;
    long stride = (long)nrid * 512;
    for (long idx = (long)rid * 512 + threadIdx.x; idx < total; idx += stride) {
        int b = (int)(idx >> 20);
        int rem = (int)(idx & 1048575);
        int i = rem >> 10, j = rem & 1023;
        if (i < 128 && j < 128) continue;        // potf(0) builds/overwrites these
        const float* a = Ks + ((long)b * 1024 + i) * 3;
        const float* bb = Ks + ((long)b * 1024 + j) * 3;
        float d0 = a[0] - bb[0], d1 = a[1] - bb[1], d2 = a[2] - bb[2];
        float dist = sqrtf(d0 * d0 + d1 * d1 + d2 * d2 + 1e-12f);
        float v = __expf(-dist);
        if (i == j) v += 1e-3f;
        C[idx] = v;
    }
}

// ---------------- potf body, 512 threads, 4x8 half-tiles -----------------------
// smem layout (floats):
//   T   [0,16896)  128x132
//   cv  [16896,17920)  128x8
//   cw  [17920,18944)  128x8
//   Pn  [18944,19968)  128x8
//   St  [19968,28416)  2 x 32x132 (o==0: Ks stage; o>0: prologue; later Lc)
//   rsd [28416,28544)
//   Wb  [28544,30848)  2 x 32x36 (padded stride 36 -> float4-aligned)
//   zs  [30848,32000)  128x9
__device__ void potf_body(float* __restrict__ C, float* __restrict__ V,
                          const float* __restrict__ KsD,
                          float* smem, int o, int last, int b) {
    int tid = threadIdx.x;
    float* A = C + (long)b * 1048576;
    float* Vp = V + (long)b * 8192;
    float (*T)[132]      = (float(*)[132])smem;
    float (*cv)[8]       = (float(*)[8])(smem + 16896);
    float (*cw)[8]       = (float(*)[8])(smem + 17920);
    float (*Pn)[8]       = (float(*)[8])(smem + 18944);
    float (*St)[32][132] = (float(*)[32][132])(smem + 19968);
    float (*Lc)[32][33]  = (float(*)[32][33])(smem + 19968);   // aliases St (disjoint in time)
    float* rsd           = smem + 28416;
    float (*Wb)[32][36]  = (float(*)[32][36])(smem + 28544);
    float (*zs)[9]       = (float(*)[9])(smem + 30848);
    float* kxs           = smem + 19968;                        // o==0: Ks stage (384 floats)

    bool active = (tid < 272);
    int ti = 0, tj = 0, hh = 0;
    if (active) { int e = tid >> 1; hh = tid & 1; ti = row_of(e); tj = e - ti * (ti + 1) / 2; }
    int r0 = ti * 8 + hh * 4, c0t = tj * 8;
    int lane = tid & 63;
    int sr = tid >> 2, slk = (tid & 3) * 8;     // prologue staging coords

    // issue prologue stage chunk 0 early (overlaps Treg load)
    if (o > 0) {
        const float* sp = A + (long)(o + sr) * 1024 + (o - 128) + slk;
        float4 v0 = *(const float4*)sp;
        float4 v1 = *(const float4*)(sp + 4);
        St[0][slk    ][sr] = v0.x; St[0][slk + 1][sr] = v0.y;
        St[0][slk + 2][sr] = v0.z; St[0][slk + 3][sr] = v0.w;
        St[0][slk + 4][sr] = v1.x; St[0][slk + 5][sr] = v1.y;
        St[0][slk + 6][sr] = v1.z; St[0][slk + 7][sr] = v1.w;
    }
    float Treg[4][8];
    if (o == 0) {
        // ---- build diag block 0 from Ks (bit-identical to old k_buildC) ----
        for (int i = tid; i < 384; i += 512) kxs[i] = KsD[(long)b * 3072 + i];
        __syncthreads();
        if (active) {
#pragma unroll
            for (int i = 0; i < 4; i++) {
#pragma unroll
                for (int j = 0; j < 8; j++) {
                    int r = r0 + i, c = c0t + j;
                    float d0 = kxs[r * 3    ] - kxs[c * 3    ];
                    float d1 = kxs[r * 3 + 1] - kxs[c * 3 + 1];
                    float d2 = kxs[r * 3 + 2] - kxs[c * 3 + 2];
                    float dist = sqrtf(d0 * d0 + d1 * d1 + d2 * d2 + 1e-12f);
                    float v = __expf(-dist);
                    if (r == c) v += 1e-3f;
                    Treg[i][j] = v;
                }
            }
        }
    } else if (active) {
        // load diag block into registers (4 rows x 8 cols per thread)
        const float* src = A + (long)(o + r0) * 1024 + o + c0t;
#pragma unroll
        for (int i = 0; i < 4; i++) {
            float4 va = *(const float4*)(src + (long)i * 1024);
            float4 vb = *(const float4*)(src + (long)i * 1024 + 4);
            Treg[i][0] = va.x; Treg[i][1] = va.y; Treg[i][2] = va.z; Treg[i][3] = va.w;
            Treg[i][4] = vb.x; Treg[i][5] = vb.y; Treg[i][6] = vb.z; Treg[i][7] = vb.w;
        }
    }
    // ---- prologue: Treg -= Lp @ Lp^T, double-buffered staging ----
    if (o > 0) {
        for (int kc = 0; kc < 4; kc++) {
            __syncthreads();                      // St[kc&1] ready
            if (kc < 3) {                         // issue next chunk now
                const float* sp = A + (long)(o + sr) * 1024 + (o - 128) + (kc + 1) * 32 + slk;
                float4 v0 = *(const float4*)sp;
                float4 v1 = *(const float4*)(sp + 4);
                int nb = (kc + 1) & 1;
                St[nb][slk    ][sr] = v0.x; St[nb][slk + 1][sr] = v0.y;
                St[nb][slk + 2][sr] = v0.z; St[nb][slk + 3][sr] = v0.w;
                St[nb][slk + 4][sr] = v1.x; St[nb][slk + 5][sr] = v1.y;
                St[nb][slk + 6][sr] = v1.z; St[nb][slk + 7][sr] = v1.w;
            }
            if (active) {
                int buf = kc & 1;
#pragma unroll 4
                for (int k = 0; k < 32; k++) {
                    float4 a0 = *(const float4*)&St[buf][k][r0];
                    float4 b0 = *(const float4*)&St[buf][k][c0t];
                    float4 b1 = *(const float4*)&St[buf][k][c0t + 4];
                    float aa[4] = {a0.x, a0.y, a0.z, a0.w};
                    float bb[8] = {b0.x, b0.y, b0.z, b0.w, b1.x, b1.y, b1.z, b1.w};
#pragma unroll
                    for (int i = 0; i < 4; i++)
#pragma unroll
                        for (int j = 0; j < 8; j++) Treg[i][j] -= aa[i] * bb[j];
                }
            }
        }
    }
    // ---- initial dump of column 0 into Pn ----
    if (active && tj == 0) {
#pragma unroll
        for (int i = 0; i < 4; i++) {
            *(float4*)&Pn[r0 + i][0] = make_float4(Treg[i][0], Treg[i][1], Treg[i][2], Treg[i][3]);
            *(float4*)&Pn[r0 + i][4] = make_float4(Treg[i][4], Treg[i][5], Treg[i][6], Treg[i][7]);
        }
    }
    __syncthreads();
    // ---- 16 rank-8 panels, 2 barriers each (R16 proven structure) ----
    for (int jbt = 0; jbt < 16; jbt++) {
        int jb = jbt * 8;
        if (tid < 64) {                           // wave-0 LDL on Pn -> cv, cw
            int r1 = lane, r2 = 64 + lane;
            float v1[8], v2[8], w1[8], w2[8];
#pragma unroll
            for (int q = 0; q < 8; q++) {
                int j = jb + q;
                int jl = j & 63;
                bool hi = (j >= 64);
                float a1 = Pn[r1][q], a2 = Pn[r2][q];
#pragma unroll
                for (int p = 0; p < 8; p++) {
                    if (p < q) {
                        float wj = __shfl(hi ? w2[p] : w1[p], jl);
                        a1 -= v1[p] * wj;
                        a2 -= v2[p] * wj;
                    }
                }
                v1[q] = a1; v2[q] = a2;
                float dj = __shfl(hi ? a2 : a1, jl);
                float dinv = 1.0f / dj;
                w1[q] = a1 * dinv; w2[q] = a2 * dinv;
            }
            *(float4*)&cv[r1][0] = make_float4(v1[0], v1[1], v1[2], v1[3]);
            *(float4*)&cv[r1][4] = make_float4(v1[4], v1[5], v1[6], v1[7]);
            *(float4*)&cv[r2][0] = make_float4(v2[0], v2[1], v2[2], v2[3]);
            *(float4*)&cv[r2][4] = make_float4(v2[4], v2[5], v2[6], v2[7]);
            *(float4*)&cw[r1][0] = make_float4(w1[0], w1[1], w1[2], w1[3]);
            *(float4*)&cw[r1][4] = make_float4(w1[4], w1[5], w1[6], w1[7]);
            *(float4*)&cw[r2][0] = make_float4(w2[0], w2[1], w2[2], w2[3]);
            *(float4*)&cw[r2][4] = make_float4(w2[4], w2[5], w2[6], w2[7]);
        }
        __syncthreads();
        if (active && tj == jbt) {                // panel owners: reload LDL column
#pragma unroll
            for (int i = 0; i < 4; i++) {
                float4 va = *(const float4*)&cv[r0 + i][0];
                float4 vb = *(const float4*)&cv[r0 + i][4];
                Treg[i][0] = va.x; Treg[i][1] = va.y; Treg[i][2] = va.z; Treg[i][3] = va.w;
                Treg[i][4] = vb.x; Treg[i][5] = vb.y; Treg[i][6] = vb.z; Treg[i][7] = vb.w;
            }
        } else if (active && tj > jbt) {          // trailing update (+ fused next dump)
#pragma unroll
            for (int h = 0; h < 2; h++) {
                float va4[4][4], wb4[8][4];
#pragma unroll
                for (int i = 0; i < 4; i++) {
                    float4 v = *(const float4*)&cv[r0 + i][h * 4];
                    va4[i][0] = v.x; va4[i][1] = v.y; va4[i][2] = v.z; va4[i][3] = v.w;
                }
#pragma unroll
                for (int j = 0; j < 8; j++) {
                    float4 v = *(const float4*)&cw[c0t + j][h * 4];
                    wb4[j][0] = v.x; wb4[j][1] = v.y; wb4[j][2] = v.z; wb4[j][3] = v.w;
                }
#pragma unroll
                for (int i = 0; i < 4; i++)
#pragma unroll
                    for (int j = 0; j < 8; j++)
                        Treg[i][j] -= va4[i][0] * wb4[j][0] + va4[i][1] * wb4[j][1]
                                    + va4[i][2] * wb4[j][2] + va4[i][3] * wb4[j][3];
            }
            if (tj == jbt + 1) {                  // next panel column -> Pn
#pragma unroll
                for (int i = 0; i < 4; i++) {
                    *(float4*)&Pn[r0 + i][0] = make_float4(Treg[i][0], Treg[i][1], Treg[i][2], Treg[i][3]);
                    *(float4*)&Pn[r0 + i][4] = make_float4(Treg[i][4], Treg[i][5], Treg[i][6], Treg[i][7]);
                }
            }
        }
        __syncthreads();
    }
    // ---- dump registers (raw LDL lower) to LDS T ----
    if (active) {
#pragma unroll
        for (int i = 0; i < 4; i++) {
            *(float4*)&T[r0 + i][c0t]     = make_float4(Treg[i][0], Treg[i][1], Treg[i][2], Treg[i][3]);
            *(float4*)&T[r0 + i][c0t + 4] = make_float4(Treg[i][4], Treg[i][5], Treg[i][6], Treg[i][7]);
        }
    }
    __syncthreads();
    // ---- LDL -> Cholesky L; ZERO upper half ----
    if (tid < 128) rsd[tid] = rsqrtf(T[tid][tid]);
    __syncthreads();
    {
        int rg = tid >> 5, cg = tid & 31;
#pragma unroll
        for (int j = 0; j < 4; j++) {
            int c = cg + 32 * j;
#pragma unroll
            for (int i = 0; i < 8; i++) {
                int r = rg * 8 + i;
                if (c <= r) T[r][c] *= rsd[c];
                else        T[r][c] = 0.0f;
            }
        }
    }
    __syncthreads();
    // ---- trtri phase 2 (waves 0..3, diag 32x32 inverses) ||
    //      snapshot of original off-diag L blocks into Lc (tid>=256) ----
    {
        int wv = tid >> 6;
        if (wv < 4 && lane < 32) {
            int d0 = wv * 32;
            int j = lane;
            float x[32];
#pragma unroll
            for (int i = 0; i < 32; i++) {
                float dinv = 1.0f / T[d0 + i][d0 + i];
                float s = 0.0f;
#pragma unroll
                for (int k = 0; k < i; k++) s += T[d0 + i][d0 + k] * x[k];
                x[i] = (i == j) ? dinv : -s * dinv;
            }
#pragma unroll
            for (int i = 0; i < 32; i++) T[d0 + i][d0 + j] = x[i];
        }
        if (tid >= 256) {
            // p = i*(i-1)/2 + kb : 0:(1,0) 1:(2,0) 2:(2,1) 3:(3,0) 4:(3,1) 5:(3,2)
            for (int idx = tid - 256; idx < 6144; idx += 256) {
                int p = idx >> 10;
                int e = idx & 1023;
                int r = e >> 5, c = e & 31;
                int i3 = (p == 0) ? 1 : (p <= 2 ? 2 : 3);
                int kb = (p == 0) ? 0 : (p <= 2 ? p - 1 : p - 3);
                Lc[p][r][c] = T[i3 * 32 + r][kb * 32 + c];
            }
        }
    }
    __syncthreads();
    // ---- trtri phase 3: two parallel teams, 3 steps, 2 barriers each. ----
    {
        int team = tid >> 8, ttid = tid & 255;
        int orr = ttid >> 3, oc = (ttid & 7) * 4;
        for (int st = 0; st < 3; st++) {
            int i3, j3;
            if (team == 0) { i3 = st + 1; j3 = 0; }
            else           { i3 = (st == 0) ? 2 : 3; j3 = (st == 2) ? 2 : 1; }
            float w0 = 0, w1 = 0, w2 = 0, w3 = 0;
            for (int kb = j3; kb < i3; kb++) {
                int p = i3 * (i3 - 1) / 2 + kb;
#pragma unroll 8
                for (int kk = 0; kk < 32; kk++) {
                    float l = Lc[p][orr][kk];
                    float4 t = *(const float4*)&T[kb * 32 + kk][j3 * 32 + oc];
                    w0 += l * t.x; w1 += l * t.y; w2 += l * t.z; w3 += l * t.w;
                }
            }
            *(float4*)&Wb[team][orr][oc] = make_float4(w0, w1, w2, w3);
            __syncthreads();
            float v0 = 0, v1 = 0, v2 = 0, v3 = 0;
#pragma unroll 8
            for (int kk = 0; kk < 32; kk++) {
                float l = T[i3 * 32 + orr][i3 * 32 + kk];
                float4 wv = *(const float4*)&Wb[team][kk][oc];
                v0 += l * wv.x; v1 += l * wv.y; v2 += l * wv.z; v3 += l * wv.w;
            }
            T[i3 * 32 + orr][j3 * 32 + oc    ] = -v0;
            T[i3 * 32 + orr][j3 * 32 + oc + 1] = -v1;
            T[i3 * 32 + orr][j3 * 32 + oc + 2] = -v2;
            T[i3 * 32 + orr][j3 * 32 + oc + 3] = -v3;
            __syncthreads();
        }
    }
    // ---- writeback Linv (exact zeros above diagonal) ----
    {
        int r = tid >> 2, c0 = (tid & 3) * 32;
        float* dst = A + (long)(o + r) * 1024 + o + c0;
#pragma unroll
        for (int k = 0; k < 8; k++) {
            int c = c0 + 4 * k;
            *(float4*)(dst + 4 * k) = make_float4(T[r][c], T[r][c + 1], T[r][c + 2], T[r][c + 3]);
        }
    }
    // ---- forward diag step: y = Linv @ z; last block also x = Linv^T y ----
    {
        int k = tid >> 2, c2 = (tid & 3) * 2;
        float2 v = *(const float2*)&Vp[(o + k) * 8 + c2];
        zs[k][c2] = v.x; zs[k][c2 + 1] = v.y;
    }
    __syncthreads();
    {
        int r = tid & 127, c2 = (tid >> 7) * 2;
        float y0 = 0, y1 = 0;
#pragma unroll 8
        for (int k = 0; k < 128; k++) {
            float l = T[r][k];
            y0 += l * zs[k][c2];
            y1 += l * zs[k][c2 + 1];
        }
        if (!last) {
            *(float2*)&Vp[(o + r) * 8 + c2] = make_float2(y0, y1);
        } else {
            __syncthreads();
            zs[r][c2] = y0; zs[r][c2 + 1] = y1;
            __syncthreads();
            float x0 = 0, x1 = 0;
#pragma unroll 8
            for (int k = 0; k < 128; k++) {
                float l = T[k][r];
                x0 += l * zs[k][c2];
                x1 += l * zs[k][c2 + 1];
            }
            *(float2*)&Vp[(o + r) * 8 + c2] = make_float2(x0, x1);
        }
    }
}

// ---------------- syrk body, 512 threads, 4x8 tiles ----------------------------
__device__ void syrk_body(float* __restrict__ C, float* smem,
                          int o, int pti, int ptj, int b) {
    float* A = C + (long)b * 1048576;
    int bi = o + 128 + pti * 128, bj = o + 128 + ptj * 128;
    float (*As)[132] = (float(*)[132])smem;
    float (*Bs)[132] = (float(*)[132])(smem + 4224);
    int tid = threadIdx.x;
    int tx = tid & 15, ty = tid >> 4;       // ty 0..31 (4-row groups)
    float acc[4][8] = {};
    int lr = tid >> 2;
    int lk = (tid & 3) * 8;
    bool diag = (bi == bj);
    for (int kc = 0; kc < 128; kc += 32) {
        {
            const float* src = A + (long)(bi + lr) * 1024 + o + kc + lk;
            float4 v0 = *(const float4*)src;
            float4 v1 = *(const float4*)(src + 4);
            As[lk    ][lr] = v0.x; As[lk + 1][lr] = v0.y;
            As[lk + 2][lr] = v0.z; As[lk + 3][lr] = v0.w;
            As[lk + 4][lr] = v1.x; As[lk + 5][lr] = v1.y;
            As[lk + 6][lr] = v1.z; As[lk + 7][lr] = v1.w;
            if (!diag) {
                const float* sb = A + (long)(bj + lr) * 1024 + o + kc + lk;
                float4 w0 = *(const float4*)sb;
                float4 w1 = *(const float4*)(sb + 4);
                Bs[lk    ][lr] = w0.x; Bs[lk + 1][lr] = w0.y;
                Bs[lk + 2][lr] = w0.z; Bs[lk + 3][lr] = w0.w;
                Bs[lk + 4][lr] = w1.x; Bs[lk + 5][lr] = w1.y;
                Bs[lk + 6][lr] = w1.z; Bs[lk + 7][lr] = w1.w;
            }
        }
        __syncthreads();
        {
            float (*Bp)[132] = diag ? As : Bs;
#pragma unroll
            for (int k = 0; k < 32; k++) {
                float4 a0 = *(const float4*)&As[k][ty * 4];
                float4 b0 = *(const float4*)&Bp[k][tx * 8];
                float4 b1 = *(const float4*)&Bp[k][tx * 8 + 4];
                float aa[4] = {a0.x, a0.y, a0.z, a0.w};
                float bb[8] = {b0.x, b0.y, b0.z, b0.w, b1.x, b1.y, b1.z, b1.w};
#pragma unroll
                for (int i = 0; i < 4; i++)
#pragma unroll
                    for (int j = 0; j < 8; j++) acc[i][j] += aa[i] * bb[j];
            }
        }
        __syncthreads();
    }
#pragma unroll
    for (int i = 0; i < 4; i++) {
        int r = bi + ty * 4 + i;
        float* dst = A + (long)r * 1024 + bj + tx * 8;
        if (!diag) {
            float4 p0 = *(const float4*)dst;
            float4 p1 = *(const float4*)(dst + 4);
            p0.x -= acc[i][0]; p0.y -= acc[i][1]; p0.z -= acc[i][2]; p0.w -= acc[i][3];
            p1.x -= acc[i][4]; p1.y -= acc[i][5]; p1.z -= acc[i][6]; p1.w -= acc[i][7];
            *(float4*)dst = p0;
            *(float4*)(dst + 4) = p1;
        } else {
#pragma unroll
            for (int j = 0; j < 8; j++) {
                int c = bj + tx * 8 + j;
                if (c <= r) dst[j] -= acc[i][j];
            }
        }
    }
}

// ---------------- zupd body: z_m -= L21_m(panel s-1) @ y_{s-1} -----------------
// L21 from global (exact trsmg store), kk ascending, single RMW subtract.
__device__ void zupd_body(const float* __restrict__ C, float* __restrict__ V,
                          float* smem, int o1, int m, int b) {
    const float* A = C + (long)b * 1048576;
    float* Vp = V + (long)b * 8192;
    float (*Lb)[129] = (float(*)[129])smem;
    float (*ys)[9]   = (float(*)[9])(smem + 16512);
    int tid = threadIdx.x;
    int o0 = o1 - 128;
    {
        int kk = tid >> 2, cc = (tid & 3) * 2;
        float2 v = *(const float2*)&Vp[(o0 + kk) * 8 + cc];
        ys[kk][cc] = v.x; ys[kk][cc + 1] = v.y;
    }
#pragma unroll
    for (int mm = 0; mm < 8; mm++) {
        int e = tid + mm * 512;
        int i = e >> 5, j4 = (e & 31) * 4;
        float4 v = *(const float4*)&A[(long)(m * 128 + i) * 1024 + o0 + j4];
        Lb[i][j4] = v.x; Lb[i][j4+1] = v.y; Lb[i][j4+2] = v.z; Lb[i][j4+3] = v.w;
    }
    __syncthreads();
    int r = tid & 127, c2 = (tid >> 7) * 2;
    float u0 = 0, u1 = 0;
#pragma unroll 8
    for (int kk = 0; kk < 128; kk++) {
        float l = Lb[r][kk];
        u0 += l * ys[kk][c2];
        u1 += l * ys[kk][c2 + 1];
    }
    float* vp = &Vp[(m * 128 + r) * 8 + c2];
    float2 old = *(const float2*)vp;
    old.x -= u0; old.y -= u1;
    *(float2*)vp = old;
}

// ---------------- fused launch: potf(s) [blocks 0-15] + syrk(s-1) pairs
// (except (0,0) -> potf prologue) + zupd riders (panel s-1 -> z_m, m=s+1..7)
// + (s==0 only) buildC riders over all of C except diag block 0 -----------------
__global__ __launch_bounds__(512) void k_potf_syrk(float* __restrict__ C,
                                                   float* __restrict__ V,
                                                   const float* __restrict__ Ks,
                                                   int o, int last, int nsy) {
    __shared__ __align__(16) float smem[32000];   // potf 128KB; syrk 33KB; zupd 69KB
    int bx = blockIdx.x;
    if (bx < 16) {
        potf_body(C, V, Ks, smem, o, last, bx);
    } else if (o == 0) {
        buildc_rider(Ks, C, bx - 16, gridDim.x - 16);
    } else if (bx < 16 + nsy) {
        int v = bx - 16;
        int bb = v & 15;
        int p = (v >> 4) + 1;             // skip pair (0,0)
        int tii = row_of(p);
        int tjj = p - tii * (tii + 1) / 2;
        syrk_body(C, smem, o - 128, tii, tjj, bb);
    } else {
        int v = bx - 16 - nsy;
        int bb = v & 15;
        int zj = v >> 4;
        int m = (o >> 7) + 1 + zj;        // m = s+1..7 (panel s-1)
        zupd_body(C, V, smem, o, m, bb);
    }
}

// ---------------- TRSM-GEMM, 512 threads; block 0 also updates z_{s+1} ---------
__global__ __launch_bounds__(512) void k_trsmg(float* __restrict__ C,
                                               float* __restrict__ V, int o) {
    int b = blockIdx.y;
    float* A = C + (long)b * 1048576;
    float* Vp = V + (long)b * 8192;
    int bi = o + 128 + blockIdx.x * 128;
    const float* Linv = A + (long)o * 1024 + o;
    __shared__ float As[32][132];
    __shared__ float Ls[32][132];   // block 0 reuses as ys (flat) in the tail
    int tid = threadIdx.x;
    int tx = tid & 15, ty = tid >> 4;       // ty 0..31
    float acc[4][8] = {};
    int lr = tid >> 2;
    int lk = (tid & 3) * 8;
    for (int kc = 0; kc < 128; kc += 32) {
        {
            const float* src = A + (long)(bi + lr) * 1024 + o + kc + lk;
            const float* sl  = Linv + (long)lr * 1024 + kc + lk;
            float4 v0 = *(const float4*)src;
            float4 v1 = *(const float4*)(src + 4);
            As[lk    ][lr] = v0.x; As[lk + 1][lr] = v0.y;
            As[lk + 2][lr] = v0.z; As[lk + 3][lr] = v0.w;
            As[lk + 4][lr] = v1.x; As[lk + 5][lr] = v1.y;
            As[lk + 6][lr] = v1.z; As[lk + 7][lr] = v1.w;
            float4 w0 = *(const float4*)sl;
            float4 w1 = *(const float4*)(sl + 4);
            Ls[lk    ][lr] = w0.x; Ls[lk + 1][lr] = w0.y;
            Ls[lk + 2][lr] = w0.z; Ls[lk + 3][lr] = w0.w;
            Ls[lk + 4][lr] = w1.x; Ls[lk + 5][lr] = w1.y;
            Ls[lk + 6][lr] = w1.z; Ls[lk + 7][lr] = w1.w;
        }
        __syncthreads();
#pragma unroll
        for (int k = 0; k < 32; k++) {
            float4 a0 = *(const float4*)&As[k][ty * 4];
            float4 b0 = *(const float4*)&Ls[k][tx * 8];
            float4 b1 = *(const float4*)&Ls[k][tx * 8 + 4];
            float aa[4] = {a0.x, a0.y, a0.z, a0.w};
            float bb[8] = {b0.x, b0.y, b0.z, b0.w, b1.x, b1.y, b1.z, b1.w};
#pragma unroll
            for (int i = 0; i < 4; i++)
#pragma unroll
                for (int j = 0; j < 8; j++) acc[i][j] += aa[i] * bb[j];
        }
        __syncthreads();
    }
#pragma unroll
    for (int i = 0; i < 4; i++) {
        float* dst = A + (long)(bi + ty * 4 + i) * 1024 + o + tx * 8;
        *(float4*)dst       = make_float4(acc[i][0], acc[i][1], acc[i][2], acc[i][3]);
        *(float4*)(dst + 4) = make_float4(acc[i][4], acc[i][5], acc[i][6], acc[i][7]);
    }
    if (blockIdx.x != 0) return;
    // tail (block 0 only): z_{s+1} -= L21(row s+1) @ y_s  (acc IS that L21)
    float* ysf = &Ls[0][0];
    {
        int k = tid >> 2, c2 = (tid & 3) * 2;
        float2 v = *(const float2*)&Vp[(o + k) * 8 + c2];
        ysf[k * 9 + c2] = v.x; ysf[k * 9 + c2 + 1] = v.y;
    }
    __syncthreads();
    float zacc0 = 0, zacc1 = 0;
    int zr = tid & 127, zc0 = (tid >> 7) * 2;
#pragma unroll
    for (int ch = 0; ch < 4; ch++) {
        if ((tx >> 2) == ch) {
            int cb = (tx & 3) * 8;
#pragma unroll
            for (int j = 0; j < 8; j++)
#pragma unroll
                for (int i = 0; i < 4; i++)
                    As[cb + j][ty * 4 + i] = acc[i][j];
        }
        __syncthreads();
#pragma unroll 8
        for (int k = 0; k < 32; k++) {
            float l = As[k][zr];
            const float* yp = &ysf[(ch * 32 + k) * 9 + zc0];
            zacc0 += l * yp[0]; zacc1 += l * yp[1];
        }
        __syncthreads();
    }
    float* vp = &Vp[(bi + zr) * 8 + zc0];
    float2 old = *(const float2*)vp;
    old.x -= zacc0; old.y -= zacc1;
    *(float2*)vp = old;
}

// ---------------- backward step k: y_j -= L_{k,j}^T x_k (j<k, parallel) --------
__global__ __launch_bounds__(512) void k_bstep(const float* __restrict__ C,
                                               float* __restrict__ V, int k) {
    int b = blockIdx.y, j = blockIdx.x, tid = threadIdx.x;
    const float* A = C + (long)b * 1048576;
    float* Vp = V + (long)b * 8192;
    __shared__ float Lb[128][129];
    __shared__ float xs[128][9];
    __shared__ float ys[128][9];
    {
        int kk = tid >> 2, c2 = (tid & 3) * 2;
        float2 v = *(const float2*)&Vp[(k * 128 + kk) * 8 + c2];
        xs[kk][c2] = v.x; xs[kk][c2 + 1] = v.y;
    }
#pragma unroll
    for (int m = 0; m < 8; m++) {
        int e = tid + m * 512;
        int i = e >> 5, j4 = (e & 31) * 4;
        float4 v = *(const float4*)&A[(long)(k * 128 + i) * 1024 + j * 128 + j4];
        Lb[i][j4] = v.x; Lb[i][j4+1] = v.y; Lb[i][j4+2] = v.z; Lb[i][j4+3] = v.w;
    }
    __syncthreads();
    int r = tid & 127, c2 = (tid >> 7) * 2;
    float u0 = 0, u1 = 0;
#pragma unroll 8
    for (int kk = 0; kk < 128; kk++) {
        float l = Lb[kk][r];
        u0 += l * xs[kk][c2];
        u1 += l * xs[kk][c2 + 1];
    }
    float* vp = &Vp[(j * 128 + r) * 8 + c2];
    float2 old = *(const float2*)vp;
    old.x -= u0; old.y -= u1;
    if (j < k - 1) {
        *(float2*)vp = old;
    } else {
        ys[r][c2] = old.x; ys[r][c2 + 1] = old.y;
        __syncthreads();
        int o = j * 128;
#pragma unroll
        for (int m = 0; m < 8; m++) {
            int e = tid + m * 512;
            int i = e >> 5, j4 = (e & 31) * 4;
            float4 v = *(const float4*)&A[(long)(o + i) * 1024 + o + j4];
            Lb[i][j4] = v.x; Lb[i][j4+1] = v.y; Lb[i][j4+2] = v.z; Lb[i][j4+3] = v.w;
        }
        __syncthreads();
        float x0 = 0, x1 = 0;
#pragma unroll 8
        for (int kk = 0; kk < 128; kk++) {
            float l = Lb[kk][r];
            x0 += l * ys[kk][c2];
            x1 += l * ys[kk][c2 + 1];
        }
        *(float2*)vp = make_float2(x0, x1);
    }
}

// ---------------- fused output: out[q,:] = sum_k exp(-d(Qs_q,Ks_k)) X[k,:] -----
__global__ void k_out(const float* __restrict__ Qs, const float* __restrict__ Ks,
                      const float* __restrict__ X, float* __restrict__ out) {
    int b = blockIdx.x >> 4;
    int qc = blockIdx.x & 15;
    int t = threadIdx.x;
    int q = t & 63, ks = t >> 6;
    __shared__ float kx[1024][3];
    __shared__ __align__(16) float xv[1024][8];
    __shared__ float red[4][64][8];
    for (int i = t; i < 3072; i += 256) kx[i / 3][i % 3] = Ks[b * 3072 + i];
    for (int i = t; i < 8192; i += 256) xv[i >> 3][i & 7] = X[b * 8192 + i];
    __syncthreads();
    int gq = b * 1024 + qc * 64 + q;
    const float* qp = Qs + (long)gq * 3;
    float qx = qp[0], qy = qp[1], qz = qp[2];
    float acc[8] = {};
    int k0 = ks * 256;
#pragma unroll 2
    for (int k = k0; k < k0 + 256; k++) {
        float dx = qx - kx[k][0], dy = qy - kx[k][1], dz = qz - kx[k][2];
        float w = __expf(-sqrtf(dx * dx + dy * dy + dz * dz + 1e-12f));
        float4 xa = *(const float4*)&xv[k][0];
        float4 xb = *(const float4*)&xv[k][4];
        acc[0] += w * xa.x; acc[1] += w * xa.y; acc[2] += w * xa.z; acc[3] += w * xa.w;
        acc[4] += w * xb.x; acc[5] += w * xb.y; acc[6] += w * xb.z; acc[7] += w * xb.w;
    }
#pragma unroll
    for (int c = 0; c < 8; c++) red[ks][q][c] = acc[c];
    __syncthreads();
    if (ks == 0) {
        float* op = out + (long)gq * 8;
#pragma unroll
        for (int c = 0; c < 8; c++)
            op[c] = red[0][q][c] + red[1][q][c] + red[2][q][c] + red[3][q][c];
    }
}

extern "C" void kernel_launch(void* const* d_in, const int* in_sizes, int n_in,
                              void* d_out, int out_size, void* d_ws, size_t ws_size,
                              hipStream_t stream) {
    const float* KEY   = (const float*)d_in[0];
    const float* VALUE = (const float*)d_in[1];
    const float* QUERY = (const float*)d_in[2];
    const float* W1w = (const float*)d_in[3];  const float* W1b = (const float*)d_in[4];
    const float* W2w = (const float*)d_in[5];  const float* W2b = (const float*)d_in[6];
    const float* W3w = (const float*)d_in[7];  const float* W3b = (const float*)d_in[8];
    const float* Wv1w = (const float*)d_in[9]; const float* Wv1b = (const float*)d_in[10];
    const float* Wv2w = (const float*)d_in[11];const float* Wv2b = (const float*)d_in[12];
    const float* Wv3w = (const float*)d_in[13];const float* Wv3b = (const float*)d_in[14];

    float* ws  = (float*)d_ws;
    float* C    = ws;                 // 16*1024*1024
    float* Ks   = C + 16777216;       // 16*1024*3
    float* Qs   = Ks + 49152;
    float* Vs   = Qs + 49152;         // 16*1024*8 (z -> y -> x in place)
    float* W2T  = Vs + 131072;
    float* Wv2T = W2T + 16384;

    float* out = (float*)d_out;

    hipLaunchKernelGGL(k_transpose, dim3(128), dim3(256), 0, stream, W2w, Wv2w, W2T, Wv2T);
    hipLaunchKernelGGL(k_mlp, dim3(2048), dim3(128), 0, stream,
                       KEY, Ks, QUERY, Qs, VALUE, Vs,
                       W1w, W1b, W2T, W2b, W3w, W3b,
                       Wv1w, Wv1b, Wv2T, Wv2b, Wv3w, Wv3b);

    // factorization + fused forward substitution: 2 launches per step.
    // launch 0 additionally carries 240 buildC riders (C minus diag block 0,
    // which potf(0) builds itself from Ks). launch s>=1: syrk(s-1) pairs +
    // zupd riders (panel s-1 -> z_m, m=s+1..7). trsmg(s) block 0 also updates
    // z_{s+1} (panel s).
    for (int s = 0; s < 8; s++) {
        int o = s * 128;
        int np = 0;
        if (s >= 1) { int ntp = 8 - s; np = ntp * (ntp + 1) / 2 - 1; }
        int nz = (s >= 1) ? (7 - s) : 0;
        int nrid = (s == 0) ? 240 : 0;
        hipLaunchKernelGGL(k_potf_syrk, dim3(16 + np * 16 + nz * 16 + nrid), dim3(512), 0, stream,
                           C, Vs, Ks, o, (s == 7) ? 1 : 0, np * 16);
        int nt = 7 - s;
        if (nt > 0)
            hipLaunchKernelGGL(k_trsmg, dim3(nt, 16), dim3(512), 0, stream, C, Vs, o);
    }
    // backward substitution: parallel right-looking (x_7 done inside last potf)
    for (int k = 7; k >= 1; k--)
        hipLaunchKernelGGL(k_bstep, dim3(k, 16), dim3(512), 0, stream, C, Vs, k);

    hipLaunchKernelGGL(k_out, dim3(256), dim3(256), 0, stream, Qs, Ks, Vs, out);
}